// Round 21
// baseline (468.540 us; speedup 1.0000x reference)
//
#include <hip/hip_runtime.h>
#include <hip/hip_bf16.h>

typedef __attribute__((ext_vector_type(4))) float f32x4;
typedef __attribute__((ext_vector_type(16))) float f32x16;
typedef __attribute__((ext_vector_type(8))) short s16x8;
typedef __attribute__((ext_vector_type(4))) short s16x4;

#define GLOAD16(g, s) __builtin_amdgcn_global_load_lds((const __attribute__((address_space(1))) void*)(g), (__attribute__((address_space(3))) void*)(s), 16, 0, 0)

static constexpr int kB    = 2;
static constexpr int kSTXT = 226;
static constexpr int kSVID = 2048;
static constexpr int kD    = 1024;
static constexpr int kS    = kSTXT + kSVID;   // 2274
static constexpr int kBS   = kB * kS;         // 4548
static constexpr int kMPAD = 4608;            // 36*128 = 18*256
static constexpr int kSPAD = 2304;            // 36*64
static constexpr int kNT64 = kSPAD / 64;      // 36

static __device__ __forceinline__ ushort f2bf(float f) {
  unsigned u = __float_as_uint(f);
  u += 0x7fffu + ((u >> 16) & 1u);            // RNE (finite data only)
  return (ushort)(u >> 16);
}
static __device__ __forceinline__ float bf2f(short x) {
  return __uint_as_float(((unsigned)(ushort)x) << 16);
}

static __device__ __forceinline__ unsigned cvt_pk_bf16(float lo, float hi) {
  unsigned r;
  asm("v_cvt_pk_bf16_f32 %0, %1, %2" : "=v"(r) : "v"(lo), "v"(hi));
  return r;
}

static __device__ __forceinline__ float fexp2(float x) {
#if __has_builtin(__builtin_amdgcn_exp2f)
  return __builtin_amdgcn_exp2f(x);           // raw v_exp_f32 (domain here: [-1e30, 11.6])
#else
  float r; asm("v_exp_f32 %0, %1" : "=v"(r) : "v"(x)); return r;
#endif
}

static __device__ __forceinline__ f32x4 mfma16(s16x8 a, s16x8 b, f32x4 c) {
  return __builtin_amdgcn_mfma_f32_16x16x32_bf16(a, b, c, 0, 0, 0);
}
static __device__ __forceinline__ f32x16 mfma32(s16x8 a, s16x8 b, f32x16 c) {
  return __builtin_amdgcn_mfma_f32_32x32x16_bf16(a, b, c, 0, 0, 0);
}

// ---------------- fused prep: weights cast + X concat/cast + AO pad + panel pad + cnt zero ----------------
__global__ __launch_bounds__(256) void k_prep(const float* __restrict__ hid, const float* __restrict__ enc,
    const float* __restrict__ wq, const float* __restrict__ wk,
    const float* __restrict__ wv, const float* __restrict__ wo,
    ushort* __restrict__ Wqkv, ushort* __restrict__ Wo,
    ushort* __restrict__ Xb, ushort* __restrict__ AO,
    ushort* __restrict__ Qb, ushort* __restrict__ Kb, ushort* __restrict__ Vt,
    int* __restrict__ cnt) {
  int bid = blockIdx.x, tid = threadIdx.x;
  if (bid < 4096) {                              // weights -> bf16
    int q = bid * 256 + tid;
    int reg = q >> 18;
    int off = (q & 262143) << 2;
    const float* sp = (reg == 0) ? wq : (reg == 1) ? wk : (reg == 2) ? wv : wo;
    float4 v = *(const float4*)(sp + off);
    ushort4 o;
    o.x = f2bf(v.x); o.y = f2bf(v.y); o.z = f2bf(v.z); o.w = f2bf(v.w);
    ushort* dst = (reg < 3) ? (Wqkv + ((size_t)reg << 20) + off) : (Wo + off);
    *(ushort4*)dst = o;
  } else if (bid < 8764) {                       // X concat+cast, AO pad rows
    int q = (bid - 4096) * 256 + tid;
    const int XQ = (kMPAD * kD) / 4;
    if (q < XQ) {
      int row = q >> 8;
      int cq = (q & 255) << 2;
      ushort4 o;
      if (row < kBS) {
        int b = row / kS, s = row - b * kS;
        const float* src = (s < kSTXT) ? (enc + (size_t)(b * kSTXT + s) * kD + cq)
                                       : (hid + (size_t)(b * kSVID + (s - kSTXT)) * kD + cq);
        float4 v = *(const float4*)src;
        o.x = f2bf(v.x); o.y = f2bf(v.y); o.z = f2bf(v.z); o.w = f2bf(v.w);
      } else {
        o.x = 0; o.y = 0; o.z = 0; o.w = 0;
      }
      *(ushort4*)(Xb + (size_t)row * kD + cq) = o;
    } else {
      int p = q - XQ;
      ushort4 z; z.x = 0; z.y = 0; z.z = 0; z.w = 0;
      *(ushort4*)(AO + (size_t)kBS * kD + (size_t)p * 4) = z;
    }
  } else if (bid < 9124) {                       // zero panel pad rows
    int id = (bid - 8764) * 256 + tid;
    int region = id / 30720;
    int r = id - region * 30720;
    if (region < 2) {
      int bh = r / 960, off = r - bh * 960;
      unsigned* p = (unsigned*)((region == 0 ? Qb : Kb) + (size_t)bh * kSPAD * 64 + (size_t)kS * 64);
      p[off] = 0u;
    } else {
      int row = r / 15, off = r - row * 15;
      unsigned* p = (unsigned*)(Vt + (size_t)row * kSPAD + kS);
      p[off] = 0u;
    }
  } else {                                       // zero the per-bq combine counters
    for (int i = tid; i < 576; i += 256) cnt[i] = 0;
  }
}

// ---------------- fused QKV GEMM + bias + LN + RoPE -> panels ----------------
// 256x128 tile, 8 waves (4M x 2N), dbuf staging with both-sides col-slot XOR swizzle.
__global__ __launch_bounds__(512) void k_gemmqkv(const ushort* __restrict__ A, const ushort* __restrict__ Bm,
    const float* __restrict__ bq, const float* __restrict__ bk, const float* __restrict__ bv,
    const float* __restrict__ lnqw, const float* __restrict__ lnqb,
    const float* __restrict__ lnkw, const float* __restrict__ lnkb,
    const float* __restrict__ cosb, const float* __restrict__ sinb,
    ushort* __restrict__ Qb, ushort* __restrict__ Kb, ushort* __restrict__ Vt) {
  __shared__ ushort lsA[2][8192];                // [256 rows][32 cols] per buffer
  __shared__ ushort lsB[2][4096];                // [128 rows][32 cols] per buffer
  const int K = 1024, nt = 24;
  int bid = blockIdx.x;
  int wg = (bid & 7) * 54 + (bid >> 3);          // XCD swizzle (432 % 8 == 0)
  int mt = wg / nt, ntl = wg - mt * nt;
  int m0 = mt << 8, n0 = ntl << 7;
  int tid = threadIdx.x;
  int w = tid >> 6, l = tid & 63;
  int wm = (w >> 1) << 6, wn = (w & 1) << 6;
  int lr = l & 15, lh = l >> 4;

  f32x4 acc[4][4] = {};

  int cA0 = tid, cA1 = tid + 512, cB = tid;
  int rA0 = cA0 >> 2, rA1 = cA1 >> 2, rB = cB >> 2;
  int sA0 = ((cA0 & 3) ^ ((cA0 >> 3) & 3)) << 3;
  int sA1 = ((cA1 & 3) ^ ((cA1 >> 3) & 3)) << 3;
  int sB  = ((cB & 3) ^ ((cB >> 3) & 3)) << 3;

#define GISSUE(buf, kk0) do {                                              \
    GLOAD16(A + (size_t)(m0 + rA0) * K + (kk0) + sA0, &lsA[buf][cA0 * 8]); \
    GLOAD16(A + (size_t)(m0 + rA1) * K + (kk0) + sA1, &lsA[buf][cA1 * 8]); \
    GLOAD16(Bm + (size_t)(n0 + rB) * K + (kk0) + sB,  &lsB[buf][cB * 8]);  \
  } while (0)

  GISSUE(0, 0);
  for (int kt = 0; kt < 32; ++kt) {
    int cur = kt & 1;
    __builtin_amdgcn_s_barrier();
    if (kt + 1 < 32) {
      GISSUE(cur ^ 1, (kt + 1) * 32);
      asm volatile("s_waitcnt vmcnt(3)" ::: "memory");
    } else {
      asm volatile("s_waitcnt vmcnt(0)" ::: "memory");
    }
    __builtin_amdgcn_s_barrier();
    __builtin_amdgcn_sched_barrier(0);
    s16x8 af[4], bfr[4];
#pragma unroll
    for (int mi = 0; mi < 4; ++mi) {
      int row = wm + mi * 16 + lr;
      int sl = lh ^ ((row >> 1) & 3);
      af[mi] = *(const s16x8*)&lsA[cur][row * 32 + sl * 8];
    }
#pragma unroll
    for (int ni = 0; ni < 4; ++ni) {
      int row = wn + ni * 16 + lr;
      int sl = lh ^ ((row >> 1) & 3);
      bfr[ni] = *(const s16x8*)&lsB[cur][row * 32 + sl * 8];
    }
    __builtin_amdgcn_s_setprio(1);
#pragma unroll
    for (int mi = 0; mi < 4; ++mi)
#pragma unroll
      for (int ni = 0; ni < 4; ++ni)
        acc[mi][ni] = mfma16(af[mi], bfr[ni], acc[mi][ni]);
    __builtin_amdgcn_s_setprio(0);
  }
#undef GISSUE

  int proj = n0 >> 10;
  int cip0 = (n0 & 1023) + wn;
  int hw = cip0 >> 6;
  const float* bias = (proj == 0) ? bq : (proj == 1) ? bk : bv;
  float bi[4];
#pragma unroll
  for (int ni = 0; ni < 4; ++ni) bi[ni] = bias[cip0 + ni * 16 + lr];

  if (proj < 2) {
    const float* lw = proj ? lnkw : lnqw;
    const float* lb = proj ? lnkb : lnqb;
    const float scale = proj ? 1.0f : 0.125f * 1.4426950408889634f;
    float w4[4], b4[4];
#pragma unroll
    for (int ni = 0; ni < 4; ++ni) { w4[ni] = lw[ni * 16 + lr]; b4[ni] = lb[ni * 16 + lr]; }
    ushort* panel = proj ? Kb : Qb;
#pragma unroll
    for (int mi = 0; mi < 4; ++mi) {
#pragma unroll
      for (int r = 0; r < 4; ++r) {
        int grow = m0 + wm + mi * 16 + lh * 4 + r;
        float v0 = acc[mi][0][r] + bi[0], v1 = acc[mi][1][r] + bi[1];
        float v2 = acc[mi][2][r] + bi[2], v3 = acc[mi][3][r] + bi[3];
        float sum = (v0 + v1) + (v2 + v3);
        sum += __shfl_xor(sum, 1); sum += __shfl_xor(sum, 2);
        sum += __shfl_xor(sum, 4); sum += __shfl_xor(sum, 8);
        float mu = sum * (1.0f / 64.0f);
        float d0 = v0 - mu, d1 = v1 - mu, d2 = v2 - mu, d3 = v3 - mu;
        float ss = (d0 * d0 + d1 * d1) + (d2 * d2 + d3 * d3);
        ss += __shfl_xor(ss, 1); ss += __shfl_xor(ss, 2);
        ss += __shfl_xor(ss, 4); ss += __shfl_xor(ss, 8);
        float rstd = rsqrtf(ss * (1.0f / 64.0f) + 1e-5f);
        float n0v = d0 * rstd * w4[0] + b4[0];
        float n1v = d1 * rstd * w4[1] + b4[1];
        float n2v = d2 * rstd * w4[2] + b4[2];
        float n3v = d3 * rstd * w4[3] + b4[3];
        int bb = grow >= kS;
        int s = grow - (bb ? kS : 0);
        bool valid = (grow < kBS) && (s < kS);
        if (valid) {
          if (s >= kSTXT) {
            int pos = s - kSTXT;
            const float* cr = cosb + (size_t)pos * 64;
            const float* sr = sinb + (size_t)pos * 64;
            float sg = (lr & 1) ? 1.0f : -1.0f;
            float p0 = __shfl_xor(n0v, 1), p1 = __shfl_xor(n1v, 1);
            float p2 = __shfl_xor(n2v, 1), p3 = __shfl_xor(n3v, 1);
            n0v = n0v * cr[lr]      + sg * p0 * sr[lr];
            n1v = n1v * cr[16 + lr] + sg * p1 * sr[16 + lr];
            n2v = n2v * cr[32 + lr] + sg * p2 * sr[32 + lr];
            n3v = n3v * cr[48 + lr] + sg * p3 * sr[48 + lr];
          }
          ushort* pr = panel + (size_t)((bb << 4) + hw) * kSPAD * 64 + (size_t)s * 64;
          pr[lr]      = f2bf(n0v * scale);
          pr[16 + lr] = f2bf(n1v * scale);
          pr[32 + lr] = f2bf(n2v * scale);
          pr[48 + lr] = f2bf(n3v * scale);
        }
      }
    }
  } else {
    bool fast = (m0 != 2048) && (m0 != 4352);
#pragma unroll
    for (int mi = 0; mi < 4; ++mi) {
      int grow0 = m0 + wm + mi * 16 + lh * 4;
#pragma unroll
      for (int ni = 0; ni < 4; ++ni) {
        int d = ni * 16 + lr;
        float f0 = acc[mi][ni][0] + bi[ni], f1 = acc[mi][ni][1] + bi[ni];
        float f2 = acc[mi][ni][2] + bi[ni], f3 = acc[mi][ni][3] + bi[ni];
        if (fast) {
          int bb = grow0 >= kS;
          int s0 = grow0 - (bb ? kS : 0);
          unsigned* pr = (unsigned*)(Vt + (size_t)((bb << 4) + hw) * 64 * kSPAD + (size_t)d * kSPAD + s0);
          pr[0] = cvt_pk_bf16(f0, f1);
          pr[1] = cvt_pk_bf16(f2, f3);
        } else {
          float fv[4] = {f0, f1, f2, f3};
#pragma unroll
          for (int j = 0; j < 4; ++j) {
            int grow = grow0 + j;
            int bb = grow >= kS;
            int s = grow - (bb ? kS : 0);
            if (grow < kBS && s < kS)
              Vt[(size_t)((bb << 4) + hw) * 64 * kSPAD + (size_t)d * kSPAD + s] = f2bf(fv[j]);
          }
        }
      }
    }
  }
}

// ---------------- out-projection GEMM (dbuf + col-slot XOR swizzle) ----------------
__global__ __launch_bounds__(256) void k_gemmo(const ushort* __restrict__ A, const ushort* __restrict__ Bm,
                                               float* __restrict__ OutF, const float* __restrict__ bias) {
  __shared__ ushort lsA[2][4096];
  __shared__ ushort lsB[2][4096];
  const int K = 1024, nt = 8;
  int mt = blockIdx.x / nt, ntl = blockIdx.x - mt * nt;
  int m0 = mt << 7, n0 = ntl << 7;
  int tid = threadIdx.x;
  int w = tid >> 6, l = tid & 63;
  int wm = (w >> 1) << 6, wn = (w & 1) << 6;
  int lr = l & 15, lh = l >> 4;

  f32x4 acc[4][4] = {};

  int c0 = w * 64 + l, c1 = c0 + 256;
  int r0 = c0 >> 2, r1 = c1 >> 2;
  int s0o = ((c0 & 3) ^ ((c0 >> 3) & 3)) << 3;
  int s1o = ((c1 & 3) ^ ((c1 >> 3) & 3)) << 3;

#define GISSUE(buf, kk0) do {                                              \
    GLOAD16(A + (size_t)(m0 + r0) * K + (kk0) + s0o, &lsA[buf][c0 * 8]);   \
    GLOAD16(A + (size_t)(m0 + r1) * K + (kk0) + s1o, &lsA[buf][c1 * 8]);   \
    GLOAD16(Bm + (size_t)(n0 + r0) * K + (kk0) + s0o, &lsB[buf][c0 * 8]);  \
    GLOAD16(Bm + (size_t)(n0 + r1) * K + (kk0) + s1o, &lsB[buf][c1 * 8]);  \
  } while (0)

  GISSUE(0, 0);
  for (int kt = 0; kt < 32; ++kt) {
    int cur = kt & 1;
    __builtin_amdgcn_s_barrier();
    if (kt + 1 < 32) {
      GISSUE(cur ^ 1, (kt + 1) * 32);
      asm volatile("s_waitcnt vmcnt(4)" ::: "memory");
    } else {
      asm volatile("s_waitcnt vmcnt(0)" ::: "memory");
    }
    __builtin_amdgcn_s_barrier();
    __builtin_amdgcn_sched_barrier(0);
    s16x8 af[4], bfr[4];
#pragma unroll
    for (int mi = 0; mi < 4; ++mi) {
      int row = wm + mi * 16 + lr;
      int sl = lh ^ ((row >> 1) & 3);
      af[mi] = *(const s16x8*)&lsA[cur][row * 32 + sl * 8];
    }
#pragma unroll
    for (int ni = 0; ni < 4; ++ni) {
      int row = wn + ni * 16 + lr;
      int sl = lh ^ ((row >> 1) & 3);
      bfr[ni] = *(const s16x8*)&lsB[cur][row * 32 + sl * 8];
    }
    __builtin_amdgcn_s_setprio(1);
#pragma unroll
    for (int mi = 0; mi < 4; ++mi)
#pragma unroll
      for (int ni = 0; ni < 4; ++ni)
        acc[mi][ni] = mfma16(af[mi], bfr[ni], acc[mi][ni]);
    __builtin_amdgcn_s_setprio(0);
  }
#undef GISSUE

#pragma unroll
  for (int mi = 0; mi < 4; ++mi) {
#pragma unroll
    for (int ni = 0; ni < 4; ++ni) {
#pragma unroll
      for (int r = 0; r < 4; ++r) {
        int row = m0 + wm + mi * 16 + lh * 4 + r;
        int col = n0 + wn + ni * 16 + lr;
        if (row < kBS) {
          float v = acc[mi][ni][r] + bias[col];
          int b = row / kS, s = row - b * kS;
          size_t o = (s >= kSTXT) ? ((size_t)(b * kSVID + s - kSTXT) * kD + col)
                                  : ((size_t)kB * kSVID * kD + (size_t)(b * kSTXT + s) * kD + col);
          OutF[o] = v;
        }
      }
    }
  }
}

// ---------------- flash attention: 32x32 MFMA, 3-way KV split, fused last-job combine ----------------
// grid 1728: (bh, qb128, sp). Fixed-base softmax; raw v_exp_f32; lsum via ones-MFMA.
// The job that finishes last for each bq (atomic counter) merges the 3 partials into AO.
__global__ __launch_bounds__(256, 4) void k_attn(const ushort* __restrict__ Q, const ushort* __restrict__ K,
                                                 const ushort* __restrict__ Vt,
                                                 ushort* __restrict__ Opb, float* __restrict__ Ml,
                                                 int* __restrict__ cnt, ushort* __restrict__ AO) {
  __shared__ ushort lsK[2][4096];          // [64 kv][64 d] XOR-swizzled
  __shared__ ushort lsVt[2][4096];         // [64 d][64 kv] XOR-swizzled
  __shared__ int lastFlag;

  int bid = blockIdx.x;
  int wg = (bid & 7) * 216 + (bid >> 3);   // XCD swizzle (1728 % 8 == 0)
  int bq = wg / 3, sp = wg - bq * 3;       // bq in [0,576): bh*18 + qb128
  int bh = bq / 18, qb = bq - bh * 18;
  const ushort* Qp = Q + (size_t)bh * kSPAD * 64;
  const char* Kg = (const char*)(K + (size_t)bh * kSPAD * 64);
  const char* Vg = (const char*)(Vt + (size_t)bh * 64 * kSPAD);

  int tid = threadIdx.x, w = tid >> 6, l = tid & 63;
  int lq = l & 31, h = l >> 5;
  int q0 = qb * 128 + w * 32;

  s16x8 aq[4];                             // Q B-frags: col=q=lq, k_in = d = 16*sl + 8h + j
#pragma unroll
  for (int sl = 0; sl < 4; ++sl)
    aq[sl] = *(const s16x8*)(Qp + (size_t)(q0 + lq) * 64 + sl * 16 + h * 8);

  s16x8 ones;                              // all-ones bf16 A-matrix for lsum MFMA
#pragma unroll
  for (int j = 0; j < 8; ++j) ones[j] = (short)0x3F80;

  f32x16 o0 = {}, o1 = {}, oL = {};        // O^T frags + lsum accumulator

  // staging: 4 x 16B chunks per thread (256 thr: K 8KB + V 8KB)
  int ksrc[2], vsrc[2], kdst[2];
#pragma unroll
  for (int i = 0; i < 2; ++i) {
    int c = tid + 256 * i;                 // chunk id [0,512)
    kdst[i] = c * 16;
    ksrc[i] = (c * 16) ^ (((c >> 3) & 7) << 4);
    int vr = c >> 3;
    vsrc[i] = vr * (kSPAD * 2) + (((c & 7) * 16) ^ ((vr & 7) << 4));
  }

#define ISSUE_TILE(buf, t) do {                                             \
    GLOAD16(Kg + (size_t)(t) * 8192 + ksrc[0], (char*)lsK[buf] + kdst[0]);  \
    GLOAD16(Kg + (size_t)(t) * 8192 + ksrc[1], (char*)lsK[buf] + kdst[1]);  \
    GLOAD16(Vg + (size_t)(t) * 128 + vsrc[0],  (char*)lsVt[buf] + kdst[0]); \
    GLOAD16(Vg + (size_t)(t) * 128 + vsrc[1],  (char*)lsVt[buf] + kdst[1]); \
  } while (0)

  int t0 = sp * 12;
  ISSUE_TILE(0, t0);

  int swz = (lq & 7) << 4;
  for (int tt = 0; tt < 12; ++tt) {
    int t = t0 + tt;
    int cur = tt & 1;
    __builtin_amdgcn_s_barrier();
    if (tt + 1 < 12) {
      ISSUE_TILE(cur ^ 1, t + 1);
      asm volatile("s_waitcnt vmcnt(4)" ::: "memory");
    } else {
      asm volatile("s_waitcnt vmcnt(0)" ::: "memory");
    }
    __builtin_amdgcn_s_barrier();
    __builtin_amdgcn_sched_barrier(0);

    // QK^T swapped (32x32x16): s0 = K[0:32] x Q^T, s1 = K[32:64] x Q^T
    f32x16 s0 = {}, s1 = {};
    __builtin_amdgcn_s_setprio(1);
#pragma unroll
    for (int sl = 0; sl < 4; ++sl) {
      int cb = h * 16 + sl * 32;
      s16x8 kf0 = *(const s16x8*)((const char*)lsK[cur] + ((lq * 128 + cb) ^ swz));
      s16x8 kf1 = *(const s16x8*)((const char*)lsK[cur] + (((lq + 32) * 128 + cb) ^ swz));
      s0 = mfma32(kf0, aq[sl], s0);
      s1 = mfma32(kf1, aq[sl], s1);
    }
    __builtin_amdgcn_s_setprio(0);

    if (t == kNT64 - 1) {                  // mask tail k >= kS (only sp=2, tt=11)
      int kv0 = t * 64;
#pragma unroll
      for (int reg = 0; reg < 16; ++reg) {
        int kl = (reg & 3) + 8 * (reg >> 2) + 4 * h;
        if (kv0 + kl >= kS) s0[reg] = -1e30f;
        if (kv0 + 32 + kl >= kS) s1[reg] = -1e30f;
      }
    }

    // fixed-base softmax: p = exp2(s), raw v_exp_f32 (|s| <= 11.54; -1e30 -> 0)
#pragma unroll
    for (int i = 0; i < 16; ++i) s0[i] = fexp2(s0[i]);
#pragma unroll
    for (int i = 0; i < 16; ++i) s1[i] = fexp2(s1[i]);

    // PV (32x32x16): per 16-k slice, P^T B-frag via 4 cvt_pk + 2 permlane32_swap;
    // lsum accumulated on the MFMA pipe via the all-ones A-matrix.
    __builtin_amdgcn_s_setprio(1);
#pragma unroll
    for (int ks2 = 0; ks2 < 4; ++ks2) {
      unsigned A0, A1, B0, B1;
      if (ks2 == 0) {
        A0 = cvt_pk_bf16(s0[0], s0[1]);  A1 = cvt_pk_bf16(s0[2], s0[3]);
        B0 = cvt_pk_bf16(s0[4], s0[5]);  B1 = cvt_pk_bf16(s0[6], s0[7]);
      } else if (ks2 == 1) {
        A0 = cvt_pk_bf16(s0[8], s0[9]);  A1 = cvt_pk_bf16(s0[10], s0[11]);
        B0 = cvt_pk_bf16(s0[12], s0[13]); B1 = cvt_pk_bf16(s0[14], s0[15]);
      } else if (ks2 == 2) {
        A0 = cvt_pk_bf16(s1[0], s1[1]);  A1 = cvt_pk_bf16(s1[2], s1[3]);
        B0 = cvt_pk_bf16(s1[4], s1[5]);  B1 = cvt_pk_bf16(s1[6], s1[7]);
      } else {
        A0 = cvt_pk_bf16(s1[8], s1[9]);  A1 = cvt_pk_bf16(s1[10], s1[11]);
        B0 = cvt_pk_bf16(s1[12], s1[13]); B1 = cvt_pk_bf16(s1[14], s1[15]);
      }
      asm volatile("v_permlane32_swap_b32 %0, %1" : "+v"(A0), "+v"(B0));
      asm volatile("v_permlane32_swap_b32 %0, %1" : "+v"(A1), "+v"(B1));
      union { unsigned u[4]; s16x8 v; } pu;
      pu.u[0] = A0; pu.u[1] = A1; pu.u[2] = B0; pu.u[3] = B1;
      int cb = h * 16 + ks2 * 32;
      s16x8 vf0 = *(const s16x8*)((const char*)lsVt[cur] + ((lq * 128 + cb) ^ swz));
      s16x8 vf1 = *(const s16x8*)((const char*)lsVt[cur] + (((lq + 32) * 128 + cb) ^ swz));
      o0 = mfma32(vf0, pu.v, o0);
      o1 = mfma32(vf1, pu.v, o1);
      oL = mfma32(ones, pu.v, oL);
    }
    __builtin_amdgcn_s_setprio(0);
  }
#undef ISSUE_TILE

  float lsum = oL[0];                      // every reg/row holds sum_k p[k][lq]

  // store bf16 partials: Opb[sp][bq][q(128)][d(64)], Ml[sp][bq][q(128)]
  ushort* op = Opb + ((size_t)(sp * 576 + bq) << 13);
  int qrow = w * 32 + lq;
#pragma unroll
  for (int g = 0; g < 4; ++g) {
    int d0 = 8 * g + 4 * h;
    uint2 pk;
    pk.x = cvt_pk_bf16(o0[4 * g], o0[4 * g + 1]);
    pk.y = cvt_pk_bf16(o0[4 * g + 2], o0[4 * g + 3]);
    *(uint2*)&op[qrow * 64 + d0] = pk;
    pk.x = cvt_pk_bf16(o1[4 * g], o1[4 * g + 1]);
    pk.y = cvt_pk_bf16(o1[4 * g + 2], o1[4 * g + 3]);
    *(uint2*)&op[qrow * 64 + 32 + d0] = pk;
  }
  float* ml = Ml + ((size_t)(sp * 576 + bq) << 7);
  if (h == 0) ml[qrow] = lsum;

  // ---- fused combine: the last-finishing job for this bq merges all 3 partials ----
  __threadfence();                         // release: our op/ml visible device-wide
  if (tid == 0) lastFlag = (atomicAdd(&cnt[bq], 1) == 2);
  __syncthreads();
  if (!lastFlag) return;
  __threadfence();                         // acquire: other jobs' op/ml visible

  {
    int b = bh >> 4, hd = bh & 15;
#pragma unroll
    for (int i = 0; i < 8; ++i) {
      int eid = i * 256 + tid;             // 2048 slots = 128q x 16 d4-groups
      int q = eid >> 4;
      int d4 = (eid & 15) << 2;
      int srow = qb * 128 + q;
      if (srow >= kS) continue;
      float den = 0.0f, e0 = 0.0f, e1 = 0.0f, e2 = 0.0f, e3 = 0.0f;
#pragma unroll
      for (int s = 0; s < 3; ++s) {
        den += Ml[((size_t)(s * 576 + bq) << 7) + q];
        uint2 pk = *(const uint2*)(Opb + ((size_t)(s * 576 + bq) << 13) + (q << 6) + d4);
        e0 += bf2f((short)(pk.x & 0xffffu));
        e1 += bf2f((short)(pk.x >> 16));
        e2 += bf2f((short)(pk.y & 0xffffu));
        e3 += bf2f((short)(pk.y >> 16));
      }
      float inv = 1.0f / den;
      uint2 opk;
      opk.x = (unsigned)f2bf(e0 * inv) | ((unsigned)f2bf(e1 * inv) << 16);
      opk.y = (unsigned)f2bf(e2 * inv) | ((unsigned)f2bf(e3 * inv) << 16);
      *(uint2*)&AO[(size_t)(b * kS + srow) * kD + hd * 64 + d4] = opk;
    }
  }
}

// ---------------- launch ----------------
extern "C" void kernel_launch(void* const* d_in, const int* in_sizes, int n_in,
                              void* d_out, int out_size, void* d_ws, size_t ws_size,
                              hipStream_t stream) {
  const float* hid  = (const float*)d_in[0];
  const float* enc  = (const float*)d_in[1];
  const float* cosb = (const float*)d_in[2];
  const float* sinb = (const float*)d_in[3];
  const float* wq   = (const float*)d_in[4];
  const float* bq   = (const float*)d_in[5];
  const float* wk   = (const float*)d_in[6];
  const float* bk   = (const float*)d_in[7];
  const float* wv   = (const float*)d_in[8];
  const float* bv   = (const float*)d_in[9];
  const float* wo   = (const float*)d_in[10];
  const float* bo   = (const float*)d_in[11];
  const float* lnqw = (const float*)d_in[12];
  const float* lnqb = (const float*)d_in[13];
  const float* lnkw = (const float*)d_in[14];
  const float* lnkb = (const float*)d_in[15];

  if (ws_size < 112197632u) return;

  char* ws = (char*)d_ws;
  ushort* Xb   = (ushort*)(ws);                  // [4608][1024] bf16
  ushort* Wqkv = (ushort*)(ws + 9437184);        // [3072][1024] bf16
  ushort* Wo   = (ushort*)(ws + 15728640);       // [1024][1024] bf16
  ushort* Vtb  = (ushort*)(ws + 17825792);       // [32][64][2304] bf16
  ushort* Opb  = (ushort*)(ws + 27262976);       // [3][576][128][64] bf16 = 28,311,552 B
  float*  Ml   = (float*)(ws + 55574528);        // [3][576][128] f32 = 884,736 B
  int*    cnt  = (int*)(ws + 67371008);          // [576] combine counters
  ushort* Qb   = (ushort*)(ws + 74448896);       // [32][2304][64] bf16
  ushort* Kb   = (ushort*)(ws + 83886080);       // [32][2304][64] bf16
  ushort* AO   = (ushort*)(ws + 102760448);      // [4608][1024] bf16

  float* out = (float*)d_out;

  k_prep<<<dim3(9125), dim3(256), 0, stream>>>(hid, enc, wq, wk, wv, wo,
      Wqkv, Wo, Xb, AO, Qb, Kb, Vtb, cnt);
  k_gemmqkv<<<dim3(432), dim3(512), 0, stream>>>(Xb, Wqkv, bq, bk, bv,
      lnqw, lnqb, lnkw, lnkb, cosb, sinb, Qb, Kb, Vtb);
  k_attn<<<dim3(1728), dim3(256), 0, stream>>>(Qb, Kb, Vtb, Opb, Ml, cnt, AO);
  k_gemmo<<<dim3(36 * 8), dim3(256), 0, stream>>>(AO, Wo, out, bo);
}

// Round 22
// 157.294 us; speedup vs baseline: 2.9787x; 2.9787x over previous
//
#include <hip/hip_runtime.h>
#include <hip/hip_bf16.h>

typedef __attribute__((ext_vector_type(4))) float f32x4;
typedef __attribute__((ext_vector_type(16))) float f32x16;
typedef __attribute__((ext_vector_type(8))) short s16x8;
typedef __attribute__((ext_vector_type(4))) short s16x4;

#define GLOAD16(g, s) __builtin_amdgcn_global_load_lds((const __attribute__((address_space(1))) void*)(g), (__attribute__((address_space(3))) void*)(s), 16, 0, 0)

static constexpr int kB    = 2;
static constexpr int kSTXT = 226;
static constexpr int kSVID = 2048;
static constexpr int kD    = 1024;
static constexpr int kS    = kSTXT + kSVID;   // 2274
static constexpr int kBS   = kB * kS;         // 4548
static constexpr int kMPAD = 4608;            // 36*128 = 18*256
static constexpr int kSPAD = 2304;            // 36*64
static constexpr int kNT64 = kSPAD / 64;      // 36

static __device__ __forceinline__ ushort f2bf(float f) {
  unsigned u = __float_as_uint(f);
  u += 0x7fffu + ((u >> 16) & 1u);            // RNE (finite data only)
  return (ushort)(u >> 16);
}
static __device__ __forceinline__ float bf2f(short x) {
  return __uint_as_float(((unsigned)(ushort)x) << 16);
}

static __device__ __forceinline__ unsigned cvt_pk_bf16(float lo, float hi) {
  unsigned r;
  asm("v_cvt_pk_bf16_f32 %0, %1, %2" : "=v"(r) : "v"(lo), "v"(hi));
  return r;
}

static __device__ __forceinline__ float fexp2(float x) {
#if __has_builtin(__builtin_amdgcn_exp2f)
  return __builtin_amdgcn_exp2f(x);           // raw v_exp_f32 (domain here: [-1e30, 11.6])
#else
  float r; asm("v_exp_f32 %0, %1" : "=v"(r) : "v"(x)); return r;
#endif
}

static __device__ __forceinline__ f32x4 mfma16(s16x8 a, s16x8 b, f32x4 c) {
  return __builtin_amdgcn_mfma_f32_16x16x32_bf16(a, b, c, 0, 0, 0);
}
static __device__ __forceinline__ f32x16 mfma32(s16x8 a, s16x8 b, f32x16 c) {
  return __builtin_amdgcn_mfma_f32_32x32x16_bf16(a, b, c, 0, 0, 0);
}

// ---------------- fused prep: weights cast + X concat/cast + AO pad + panel pad ----------------
__global__ __launch_bounds__(256) void k_prep(const float* __restrict__ hid, const float* __restrict__ enc,
    const float* __restrict__ wq, const float* __restrict__ wk,
    const float* __restrict__ wv, const float* __restrict__ wo,
    ushort* __restrict__ Wqkv, ushort* __restrict__ Wo,
    ushort* __restrict__ Xb, ushort* __restrict__ AO,
    ushort* __restrict__ Qb, ushort* __restrict__ Kb, ushort* __restrict__ Vt) {
  int bid = blockIdx.x, tid = threadIdx.x;
  if (bid < 4096) {                              // weights -> bf16
    int q = bid * 256 + tid;
    int reg = q >> 18;
    int off = (q & 262143) << 2;
    const float* sp = (reg == 0) ? wq : (reg == 1) ? wk : (reg == 2) ? wv : wo;
    float4 v = *(const float4*)(sp + off);
    ushort4 o;
    o.x = f2bf(v.x); o.y = f2bf(v.y); o.z = f2bf(v.z); o.w = f2bf(v.w);
    ushort* dst = (reg < 3) ? (Wqkv + ((size_t)reg << 20) + off) : (Wo + off);
    *(ushort4*)dst = o;
  } else if (bid < 8764) {                       // X concat+cast, AO pad rows
    int q = (bid - 4096) * 256 + tid;
    const int XQ = (kMPAD * kD) / 4;
    if (q < XQ) {
      int row = q >> 8;
      int cq = (q & 255) << 2;
      ushort4 o;
      if (row < kBS) {
        int b = row / kS, s = row - b * kS;
        const float* src = (s < kSTXT) ? (enc + (size_t)(b * kSTXT + s) * kD + cq)
                                       : (hid + (size_t)(b * kSVID + (s - kSTXT)) * kD + cq);
        float4 v = *(const float4*)src;
        o.x = f2bf(v.x); o.y = f2bf(v.y); o.z = f2bf(v.z); o.w = f2bf(v.w);
      } else {
        o.x = 0; o.y = 0; o.z = 0; o.w = 0;
      }
      *(ushort4*)(Xb + (size_t)row * kD + cq) = o;
    } else {
      int p = q - XQ;
      ushort4 z; z.x = 0; z.y = 0; z.z = 0; z.w = 0;
      *(ushort4*)(AO + (size_t)kBS * kD + (size_t)p * 4) = z;
    }
  } else {                                       // zero panel pad rows
    int id = (bid - 8764) * 256 + tid;
    int region = id / 30720;
    int r = id - region * 30720;
    if (region < 2) {
      int bh = r / 960, off = r - bh * 960;
      unsigned* p = (unsigned*)((region == 0 ? Qb : Kb) + (size_t)bh * kSPAD * 64 + (size_t)kS * 64);
      p[off] = 0u;
    } else {
      int row = r / 15, off = r - row * 15;
      unsigned* p = (unsigned*)(Vt + (size_t)row * kSPAD + kS);
      p[off] = 0u;
    }
  }
}

// ---------------- fused QKV GEMM + bias + LN + RoPE -> panels ----------------
// 256x128 tile, 8 waves (4M x 2N), dbuf staging with both-sides col-slot XOR swizzle.
__global__ __launch_bounds__(512) void k_gemmqkv(const ushort* __restrict__ A, const ushort* __restrict__ Bm,
    const float* __restrict__ bq, const float* __restrict__ bk, const float* __restrict__ bv,
    const float* __restrict__ lnqw, const float* __restrict__ lnqb,
    const float* __restrict__ lnkw, const float* __restrict__ lnkb,
    const float* __restrict__ cosb, const float* __restrict__ sinb,
    ushort* __restrict__ Qb, ushort* __restrict__ Kb, ushort* __restrict__ Vt) {
  __shared__ ushort lsA[2][8192];                // [256 rows][32 cols] per buffer
  __shared__ ushort lsB[2][4096];                // [128 rows][32 cols] per buffer
  const int K = 1024, nt = 24;
  int bid = blockIdx.x;
  int wg = (bid & 7) * 54 + (bid >> 3);          // XCD swizzle (432 % 8 == 0)
  int mt = wg / nt, ntl = wg - mt * nt;
  int m0 = mt << 8, n0 = ntl << 7;
  int tid = threadIdx.x;
  int w = tid >> 6, l = tid & 63;
  int wm = (w >> 1) << 6, wn = (w & 1) << 6;
  int lr = l & 15, lh = l >> 4;

  f32x4 acc[4][4] = {};

  int cA0 = tid, cA1 = tid + 512, cB = tid;
  int rA0 = cA0 >> 2, rA1 = cA1 >> 2, rB = cB >> 2;
  int sA0 = ((cA0 & 3) ^ ((cA0 >> 3) & 3)) << 3;
  int sA1 = ((cA1 & 3) ^ ((cA1 >> 3) & 3)) << 3;
  int sB  = ((cB & 3) ^ ((cB >> 3) & 3)) << 3;

#define GISSUE(buf, kk0) do {                                              \
    GLOAD16(A + (size_t)(m0 + rA0) * K + (kk0) + sA0, &lsA[buf][cA0 * 8]); \
    GLOAD16(A + (size_t)(m0 + rA1) * K + (kk0) + sA1, &lsA[buf][cA1 * 8]); \
    GLOAD16(Bm + (size_t)(n0 + rB) * K + (kk0) + sB,  &lsB[buf][cB * 8]);  \
  } while (0)

  GISSUE(0, 0);
  for (int kt = 0; kt < 32; ++kt) {
    int cur = kt & 1;
    __builtin_amdgcn_s_barrier();
    if (kt + 1 < 32) {
      GISSUE(cur ^ 1, (kt + 1) * 32);
      asm volatile("s_waitcnt vmcnt(3)" ::: "memory");
    } else {
      asm volatile("s_waitcnt vmcnt(0)" ::: "memory");
    }
    __builtin_amdgcn_s_barrier();
    __builtin_amdgcn_sched_barrier(0);
    s16x8 af[4], bfr[4];
#pragma unroll
    for (int mi = 0; mi < 4; ++mi) {
      int row = wm + mi * 16 + lr;
      int sl = lh ^ ((row >> 1) & 3);
      af[mi] = *(const s16x8*)&lsA[cur][row * 32 + sl * 8];
    }
#pragma unroll
    for (int ni = 0; ni < 4; ++ni) {
      int row = wn + ni * 16 + lr;
      int sl = lh ^ ((row >> 1) & 3);
      bfr[ni] = *(const s16x8*)&lsB[cur][row * 32 + sl * 8];
    }
    __builtin_amdgcn_s_setprio(1);
#pragma unroll
    for (int mi = 0; mi < 4; ++mi)
#pragma unroll
      for (int ni = 0; ni < 4; ++ni)
        acc[mi][ni] = mfma16(af[mi], bfr[ni], acc[mi][ni]);
    __builtin_amdgcn_s_setprio(0);
  }
#undef GISSUE

  int proj = n0 >> 10;
  int cip0 = (n0 & 1023) + wn;
  int hw = cip0 >> 6;
  const float* bias = (proj == 0) ? bq : (proj == 1) ? bk : bv;
  float bi[4];
#pragma unroll
  for (int ni = 0; ni < 4; ++ni) bi[ni] = bias[cip0 + ni * 16 + lr];

  if (proj < 2) {
    const float* lw = proj ? lnkw : lnqw;
    const float* lb = proj ? lnkb : lnqb;
    const float scale = proj ? 1.0f : 0.125f * 1.4426950408889634f;
    float w4[4], b4[4];
#pragma unroll
    for (int ni = 0; ni < 4; ++ni) { w4[ni] = lw[ni * 16 + lr]; b4[ni] = lb[ni * 16 + lr]; }
    ushort* panel = proj ? Kb : Qb;
#pragma unroll
    for (int mi = 0; mi < 4; ++mi) {
#pragma unroll
      for (int r = 0; r < 4; ++r) {
        int grow = m0 + wm + mi * 16 + lh * 4 + r;
        float v0 = acc[mi][0][r] + bi[0], v1 = acc[mi][1][r] + bi[1];
        float v2 = acc[mi][2][r] + bi[2], v3 = acc[mi][3][r] + bi[3];
        float sum = (v0 + v1) + (v2 + v3);
        sum += __shfl_xor(sum, 1); sum += __shfl_xor(sum, 2);
        sum += __shfl_xor(sum, 4); sum += __shfl_xor(sum, 8);
        float mu = sum * (1.0f / 64.0f);
        float d0 = v0 - mu, d1 = v1 - mu, d2 = v2 - mu, d3 = v3 - mu;
        float ss = (d0 * d0 + d1 * d1) + (d2 * d2 + d3 * d3);
        ss += __shfl_xor(ss, 1); ss += __shfl_xor(ss, 2);
        ss += __shfl_xor(ss, 4); ss += __shfl_xor(ss, 8);
        float rstd = rsqrtf(ss * (1.0f / 64.0f) + 1e-5f);
        float n0v = d0 * rstd * w4[0] + b4[0];
        float n1v = d1 * rstd * w4[1] + b4[1];
        float n2v = d2 * rstd * w4[2] + b4[2];
        float n3v = d3 * rstd * w4[3] + b4[3];
        int bb = grow >= kS;
        int s = grow - (bb ? kS : 0);
        bool valid = (grow < kBS) && (s < kS);
        if (valid) {
          if (s >= kSTXT) {
            int pos = s - kSTXT;
            const float* cr = cosb + (size_t)pos * 64;
            const float* sr = sinb + (size_t)pos * 64;
            float sg = (lr & 1) ? 1.0f : -1.0f;
            float p0 = __shfl_xor(n0v, 1), p1 = __shfl_xor(n1v, 1);
            float p2 = __shfl_xor(n2v, 1), p3 = __shfl_xor(n3v, 1);
            n0v = n0v * cr[lr]      + sg * p0 * sr[lr];
            n1v = n1v * cr[16 + lr] + sg * p1 * sr[16 + lr];
            n2v = n2v * cr[32 + lr] + sg * p2 * sr[32 + lr];
            n3v = n3v * cr[48 + lr] + sg * p3 * sr[48 + lr];
          }
          ushort* pr = panel + (size_t)((bb << 4) + hw) * kSPAD * 64 + (size_t)s * 64;
          pr[lr]      = f2bf(n0v * scale);
          pr[16 + lr] = f2bf(n1v * scale);
          pr[32 + lr] = f2bf(n2v * scale);
          pr[48 + lr] = f2bf(n3v * scale);
        }
      }
    }
  } else {
    bool fast = (m0 != 2048) && (m0 != 4352);
#pragma unroll
    for (int mi = 0; mi < 4; ++mi) {
      int grow0 = m0 + wm + mi * 16 + lh * 4;
#pragma unroll
      for (int ni = 0; ni < 4; ++ni) {
        int d = ni * 16 + lr;
        float f0 = acc[mi][ni][0] + bi[ni], f1 = acc[mi][ni][1] + bi[ni];
        float f2 = acc[mi][ni][2] + bi[ni], f3 = acc[mi][ni][3] + bi[ni];
        if (fast) {
          int bb = grow0 >= kS;
          int s0 = grow0 - (bb ? kS : 0);
          unsigned* pr = (unsigned*)(Vt + (size_t)((bb << 4) + hw) * 64 * kSPAD + (size_t)d * kSPAD + s0);
          pr[0] = cvt_pk_bf16(f0, f1);
          pr[1] = cvt_pk_bf16(f2, f3);
        } else {
          float fv[4] = {f0, f1, f2, f3};
#pragma unroll
          for (int j = 0; j < 4; ++j) {
            int grow = grow0 + j;
            int bb = grow >= kS;
            int s = grow - (bb ? kS : 0);
            if (grow < kBS && s < kS)
              Vt[(size_t)((bb << 4) + hw) * 64 * kSPAD + (size_t)d * kSPAD + s] = f2bf(fv[j]);
          }
        }
      }
    }
  }
}

// ---------------- out-projection GEMM (dbuf + col-slot XOR swizzle) ----------------
__global__ __launch_bounds__(256) void k_gemmo(const ushort* __restrict__ A, const ushort* __restrict__ Bm,
                                               float* __restrict__ OutF, const float* __restrict__ bias) {
  __shared__ ushort lsA[2][4096];
  __shared__ ushort lsB[2][4096];
  const int K = 1024, nt = 8;
  int mt = blockIdx.x / nt, ntl = blockIdx.x - mt * nt;
  int m0 = mt << 7, n0 = ntl << 7;
  int tid = threadIdx.x;
  int w = tid >> 6, l = tid & 63;
  int wm = (w >> 1) << 6, wn = (w & 1) << 6;
  int lr = l & 15, lh = l >> 4;

  f32x4 acc[4][4] = {};

  int c0 = w * 64 + l, c1 = c0 + 256;
  int r0 = c0 >> 2, r1 = c1 >> 2;
  int s0o = ((c0 & 3) ^ ((c0 >> 3) & 3)) << 3;
  int s1o = ((c1 & 3) ^ ((c1 >> 3) & 3)) << 3;

#define GISSUE(buf, kk0) do {                                              \
    GLOAD16(A + (size_t)(m0 + r0) * K + (kk0) + s0o, &lsA[buf][c0 * 8]);   \
    GLOAD16(A + (size_t)(m0 + r1) * K + (kk0) + s1o, &lsA[buf][c1 * 8]);   \
    GLOAD16(Bm + (size_t)(n0 + r0) * K + (kk0) + s0o, &lsB[buf][c0 * 8]);  \
    GLOAD16(Bm + (size_t)(n0 + r1) * K + (kk0) + s1o, &lsB[buf][c1 * 8]);  \
  } while (0)

  GISSUE(0, 0);
  for (int kt = 0; kt < 32; ++kt) {
    int cur = kt & 1;
    __builtin_amdgcn_s_barrier();
    if (kt + 1 < 32) {
      GISSUE(cur ^ 1, (kt + 1) * 32);
      asm volatile("s_waitcnt vmcnt(4)" ::: "memory");
    } else {
      asm volatile("s_waitcnt vmcnt(0)" ::: "memory");
    }
    __builtin_amdgcn_s_barrier();
    __builtin_amdgcn_sched_barrier(0);
    s16x8 af[4], bfr[4];
#pragma unroll
    for (int mi = 0; mi < 4; ++mi) {
      int row = wm + mi * 16 + lr;
      int sl = lh ^ ((row >> 1) & 3);
      af[mi] = *(const s16x8*)&lsA[cur][row * 32 + sl * 8];
    }
#pragma unroll
    for (int ni = 0; ni < 4; ++ni) {
      int row = wn + ni * 16 + lr;
      int sl = lh ^ ((row >> 1) & 3);
      bfr[ni] = *(const s16x8*)&lsB[cur][row * 32 + sl * 8];
    }
    __builtin_amdgcn_s_setprio(1);
#pragma unroll
    for (int mi = 0; mi < 4; ++mi)
#pragma unroll
      for (int ni = 0; ni < 4; ++ni)
        acc[mi][ni] = mfma16(af[mi], bfr[ni], acc[mi][ni]);
    __builtin_amdgcn_s_setprio(0);
  }
#undef GISSUE

#pragma unroll
  for (int mi = 0; mi < 4; ++mi) {
#pragma unroll
    for (int ni = 0; ni < 4; ++ni) {
#pragma unroll
      for (int r = 0; r < 4; ++r) {
        int row = m0 + wm + mi * 16 + lh * 4 + r;
        int col = n0 + wn + ni * 16 + lr;
        if (row < kBS) {
          float v = acc[mi][ni][r] + bias[col];
          int b = row / kS, s = row - b * kS;
          size_t o = (s >= kSTXT) ? ((size_t)(b * kSVID + s - kSTXT) * kD + col)
                                  : ((size_t)kB * kSVID * kD + (size_t)(b * kSTXT + s) * kD + col);
          OutF[o] = v;
        }
      }
    }
  }
}

// ---------------- flash attention: 32x32 MFMA, static 3-way KV split (12 tiles/job) ----------------
// grid 1728: (bh, qb128, sp). Fixed-base softmax; raw v_exp_f32; lsum via ones-MFMA.
__global__ __launch_bounds__(256, 4) void k_attn(const ushort* __restrict__ Q, const ushort* __restrict__ K,
                                                 const ushort* __restrict__ Vt,
                                                 ushort* __restrict__ Opb, float* __restrict__ Ml) {
  __shared__ ushort lsK[2][4096];          // [64 kv][64 d] XOR-swizzled
  __shared__ ushort lsVt[2][4096];         // [64 d][64 kv] XOR-swizzled

  int bid = blockIdx.x;
  int wg = (bid & 7) * 216 + (bid >> 3);   // XCD swizzle (1728 % 8 == 0)
  int bq = wg / 3, sp = wg - bq * 3;       // bq in [0,576): bh*18 + qb128
  int bh = bq / 18, qb = bq - bh * 18;
  const ushort* Qp = Q + (size_t)bh * kSPAD * 64;
  const char* Kg = (const char*)(K + (size_t)bh * kSPAD * 64);
  const char* Vg = (const char*)(Vt + (size_t)bh * 64 * kSPAD);

  int tid = threadIdx.x, w = tid >> 6, l = tid & 63;
  int lq = l & 31, h = l >> 5;
  int q0 = qb * 128 + w * 32;

  s16x8 aq[4];                             // Q B-frags: col=q=lq, k_in = d = 16*sl + 8h + j
#pragma unroll
  for (int sl = 0; sl < 4; ++sl)
    aq[sl] = *(const s16x8*)(Qp + (size_t)(q0 + lq) * 64 + sl * 16 + h * 8);

  s16x8 ones;                              // all-ones bf16 A-matrix for lsum MFMA
#pragma unroll
  for (int j = 0; j < 8; ++j) ones[j] = (short)0x3F80;

  f32x16 o0 = {}, o1 = {}, oL = {};        // O^T frags + lsum accumulator

  // staging: 4 x 16B chunks per thread (256 thr: K 8KB + V 8KB)
  int ksrc[2], vsrc[2], kdst[2];
#pragma unroll
  for (int i = 0; i < 2; ++i) {
    int c = tid + 256 * i;                 // chunk id [0,512)
    kdst[i] = c * 16;
    ksrc[i] = (c * 16) ^ (((c >> 3) & 7) << 4);
    int vr = c >> 3;
    vsrc[i] = vr * (kSPAD * 2) + (((c & 7) * 16) ^ ((vr & 7) << 4));
  }

#define ISSUE_TILE(buf, t) do {                                             \
    GLOAD16(Kg + (size_t)(t) * 8192 + ksrc[0], (char*)lsK[buf] + kdst[0]);  \
    GLOAD16(Kg + (size_t)(t) * 8192 + ksrc[1], (char*)lsK[buf] + kdst[1]);  \
    GLOAD16(Vg + (size_t)(t) * 128 + vsrc[0],  (char*)lsVt[buf] + kdst[0]); \
    GLOAD16(Vg + (size_t)(t) * 128 + vsrc[1],  (char*)lsVt[buf] + kdst[1]); \
  } while (0)

  int t0 = sp * 12;
  ISSUE_TILE(0, t0);

  int swz = (lq & 7) << 4;
  for (int tt = 0; tt < 12; ++tt) {
    int t = t0 + tt;
    int cur = tt & 1;
    __builtin_amdgcn_s_barrier();
    if (tt + 1 < 12) {
      ISSUE_TILE(cur ^ 1, t + 1);
      asm volatile("s_waitcnt vmcnt(4)" ::: "memory");
    } else {
      asm volatile("s_waitcnt vmcnt(0)" ::: "memory");
    }
    __builtin_amdgcn_s_barrier();
    __builtin_amdgcn_sched_barrier(0);

    // QK^T swapped (32x32x16): s0 = K[0:32] x Q^T, s1 = K[32:64] x Q^T
    f32x16 s0 = {}, s1 = {};
    __builtin_amdgcn_s_setprio(1);
#pragma unroll
    for (int sl = 0; sl < 4; ++sl) {
      int cb = h * 16 + sl * 32;
      s16x8 kf0 = *(const s16x8*)((const char*)lsK[cur] + ((lq * 128 + cb) ^ swz));
      s16x8 kf1 = *(const s16x8*)((const char*)lsK[cur] + (((lq + 32) * 128 + cb) ^ swz));
      s0 = mfma32(kf0, aq[sl], s0);
      s1 = mfma32(kf1, aq[sl], s1);
    }
    __builtin_amdgcn_s_setprio(0);

    if (t == kNT64 - 1) {                  // mask tail k >= kS (only sp=2, tt=11)
      int kv0 = t * 64;
#pragma unroll
      for (int reg = 0; reg < 16; ++reg) {
        int kl = (reg & 3) + 8 * (reg >> 2) + 4 * h;
        if (kv0 + kl >= kS) s0[reg] = -1e30f;
        if (kv0 + 32 + kl >= kS) s1[reg] = -1e30f;
      }
    }

    // fixed-base softmax: p = exp2(s), raw v_exp_f32 (|s| <= 11.54; -1e30 -> 0)
#pragma unroll
    for (int i = 0; i < 16; ++i) s0[i] = fexp2(s0[i]);
#pragma unroll
    for (int i = 0; i < 16; ++i) s1[i] = fexp2(s1[i]);

    // PV (32x32x16): per 16-k slice, P^T B-frag via 4 cvt_pk + 2 permlane32_swap;
    // lsum accumulated on the MFMA pipe via the all-ones A-matrix.
    __builtin_amdgcn_s_setprio(1);
#pragma unroll
    for (int ks2 = 0; ks2 < 4; ++ks2) {
      unsigned A0, A1, B0, B1;
      if (ks2 == 0) {
        A0 = cvt_pk_bf16(s0[0], s0[1]);  A1 = cvt_pk_bf16(s0[2], s0[3]);
        B0 = cvt_pk_bf16(s0[4], s0[5]);  B1 = cvt_pk_bf16(s0[6], s0[7]);
      } else if (ks2 == 1) {
        A0 = cvt_pk_bf16(s0[8], s0[9]);  A1 = cvt_pk_bf16(s0[10], s0[11]);
        B0 = cvt_pk_bf16(s0[12], s0[13]); B1 = cvt_pk_bf16(s0[14], s0[15]);
      } else if (ks2 == 2) {
        A0 = cvt_pk_bf16(s1[0], s1[1]);  A1 = cvt_pk_bf16(s1[2], s1[3]);
        B0 = cvt_pk_bf16(s1[4], s1[5]);  B1 = cvt_pk_bf16(s1[6], s1[7]);
      } else {
        A0 = cvt_pk_bf16(s1[8], s1[9]);  A1 = cvt_pk_bf16(s1[10], s1[11]);
        B0 = cvt_pk_bf16(s1[12], s1[13]); B1 = cvt_pk_bf16(s1[14], s1[15]);
      }
      asm volatile("v_permlane32_swap_b32 %0, %1" : "+v"(A0), "+v"(B0));
      asm volatile("v_permlane32_swap_b32 %0, %1" : "+v"(A1), "+v"(B1));
      union { unsigned u[4]; s16x8 v; } pu;
      pu.u[0] = A0; pu.u[1] = A1; pu.u[2] = B0; pu.u[3] = B1;
      int cb = h * 16 + ks2 * 32;
      s16x8 vf0 = *(const s16x8*)((const char*)lsVt[cur] + ((lq * 128 + cb) ^ swz));
      s16x8 vf1 = *(const s16x8*)((const char*)lsVt[cur] + (((lq + 32) * 128 + cb) ^ swz));
      o0 = mfma32(vf0, pu.v, o0);
      o1 = mfma32(vf1, pu.v, o1);
      oL = mfma32(ones, pu.v, oL);
    }
    __builtin_amdgcn_s_setprio(0);
  }
#undef ISSUE_TILE

  float lsum = oL[0];                      // every reg/row holds sum_k p[k][lq]

  // store bf16 partials: Opb[sp][bq][q(128)][d(64)], Ml[sp][bq][q(128)]
  ushort* op = Opb + ((size_t)(sp * 576 + bq) << 13);
  int qrow = w * 32 + lq;
#pragma unroll
  for (int g = 0; g < 4; ++g) {
    int d0 = 8 * g + 4 * h;
    uint2 pk;
    pk.x = cvt_pk_bf16(o0[4 * g], o0[4 * g + 1]);
    pk.y = cvt_pk_bf16(o0[4 * g + 2], o0[4 * g + 3]);
    *(uint2*)&op[qrow * 64 + d0] = pk;
    pk.x = cvt_pk_bf16(o1[4 * g], o1[4 * g + 1]);
    pk.y = cvt_pk_bf16(o1[4 * g + 2], o1[4 * g + 3]);
    *(uint2*)&op[qrow * 64 + 32 + d0] = pk;
  }
  float* ml = Ml + ((size_t)(sp * 576 + bq) << 7);
  if (h == 0) ml[qrow] = lsum;
}

// ---------------- combine 3-way split-KV partials -> AO bf16 (fixed base: plain sums) ----------------
__global__ __launch_bounds__(256) void k_combine(const ushort* __restrict__ Opb, const float* __restrict__ Ml,
                                                 ushort* __restrict__ AO) {
  int bq = blockIdx.x;                     // 576 = 32bh x 18 q-blocks
  int bh = bq / 18, q128 = bq - bh * 18;
  int b = bh >> 4, hd = bh & 15;
  int tid = threadIdx.x;
#pragma unroll
  for (int i = 0; i < 8; ++i) {
    int eid = i * 256 + tid;               // 2048 slots = 128q x 16 d4-groups
    int q = eid >> 4;
    int d4 = (eid & 15) << 2;
    int srow = q128 * 128 + q;
    if (srow >= kS) continue;
    float den = 0.0f, e0 = 0.0f, e1 = 0.0f, e2 = 0.0f, e3 = 0.0f;
#pragma unroll
    for (int s = 0; s < 3; ++s) {
      den += Ml[((size_t)(s * 576 + bq) << 7) + q];
      uint2 pk = *(const uint2*)(Opb + ((size_t)(s * 576 + bq) << 13) + (q << 6) + d4);
      e0 += bf2f((short)(pk.x & 0xffffu));
      e1 += bf2f((short)(pk.x >> 16));
      e2 += bf2f((short)(pk.y & 0xffffu));
      e3 += bf2f((short)(pk.y >> 16));
    }
    float inv = 1.0f / den;
    uint2 opk;
    opk.x = (unsigned)f2bf(e0 * inv) | ((unsigned)f2bf(e1 * inv) << 16);
    opk.y = (unsigned)f2bf(e2 * inv) | ((unsigned)f2bf(e3 * inv) << 16);
    *(uint2*)&AO[(size_t)(b * kS + srow) * kD + hd * 64 + d4] = opk;
  }
}

// ---------------- launch ----------------
extern "C" void kernel_launch(void* const* d_in, const int* in_sizes, int n_in,
                              void* d_out, int out_size, void* d_ws, size_t ws_size,
                              hipStream_t stream) {
  const float* hid  = (const float*)d_in[0];
  const float* enc  = (const float*)d_in[1];
  const float* cosb = (const float*)d_in[2];
  const float* sinb = (const float*)d_in[3];
  const float* wq   = (const float*)d_in[4];
  const float* bq   = (const float*)d_in[5];
  const float* wk   = (const float*)d_in[6];
  const float* bk   = (const float*)d_in[7];
  const float* wv   = (const float*)d_in[8];
  const float* bv   = (const float*)d_in[9];
  const float* wo   = (const float*)d_in[10];
  const float* bo   = (const float*)d_in[11];
  const float* lnqw = (const float*)d_in[12];
  const float* lnqb = (const float*)d_in[13];
  const float* lnkw = (const float*)d_in[14];
  const float* lnkb = (const float*)d_in[15];

  if (ws_size < 112197632u) return;

  char* ws = (char*)d_ws;
  ushort* Xb   = (ushort*)(ws);                  // [4608][1024] bf16
  ushort* Wqkv = (ushort*)(ws + 9437184);        // [3072][1024] bf16
  ushort* Wo   = (ushort*)(ws + 15728640);       // [1024][1024] bf16
  ushort* Vtb  = (ushort*)(ws + 17825792);       // [32][64][2304] bf16
  ushort* Opb  = (ushort*)(ws + 27262976);       // [3][576][128][64] bf16 = 28,311,552 B
  float*  Ml   = (float*)(ws + 55574528);        // [3][576][128] f32 = 884,736 B
  ushort* Qb   = (ushort*)(ws + 74448896);       // [32][2304][64] bf16
  ushort* Kb   = (ushort*)(ws + 83886080);       // [32][2304][64] bf16
  ushort* AO   = (ushort*)(ws + 102760448);      // [4608][1024] bf16

  float* out = (float*)d_out;

  k_prep<<<dim3(9124), dim3(256), 0, stream>>>(hid, enc, wq, wk, wv, wo,
      Wqkv, Wo, Xb, AO, Qb, Kb, Vtb);
  k_gemmqkv<<<dim3(432), dim3(512), 0, stream>>>(Xb, Wqkv, bq, bk, bv,
      lnqw, lnqb, lnkw, lnkb, cosb, sinb, Qb, Kb, Vtb);
  k_attn<<<dim3(1728), dim3(256), 0, stream>>>(Qb, Kb, Vtb, Opb, Ml);
  k_combine<<<dim3(576), dim3(256), 0, stream>>>(Opb, Ml, AO);
  k_gemmo<<<dim3(36 * 8), dim3(256), 0, stream>>>(AO, Wo, out, bo);
}

// Round 23
// 149.393 us; speedup vs baseline: 3.1363x; 1.0529x over previous
//
#include <hip/hip_runtime.h>
#include <hip/hip_bf16.h>

typedef __attribute__((ext_vector_type(4))) float f32x4;
typedef __attribute__((ext_vector_type(16))) float f32x16;
typedef __attribute__((ext_vector_type(8))) short s16x8;
typedef __attribute__((ext_vector_type(4))) short s16x4;

#define GLOAD16(g, s) __builtin_amdgcn_global_load_lds((const __attribute__((address_space(1))) void*)(g), (__attribute__((address_space(3))) void*)(s), 16, 0, 0)

static constexpr int kB    = 2;
static constexpr int kSTXT = 226;
static constexpr int kSVID = 2048;
static constexpr int kD    = 1024;
static constexpr int kS    = kSTXT + kSVID;   // 2274
static constexpr int kBS   = kB * kS;         // 4548
static constexpr int kMPAD = 4608;            // 36*128 = 18*256
static constexpr int kSPAD = 2304;            // 36*64
static constexpr int kNT64 = kSPAD / 64;      // 36

static __device__ __forceinline__ ushort f2bf(float f) {
  unsigned u = __float_as_uint(f);
  u += 0x7fffu + ((u >> 16) & 1u);            // RNE (finite data only)
  return (ushort)(u >> 16);
}
static __device__ __forceinline__ float bf2f(short x) {
  return __uint_as_float(((unsigned)(ushort)x) << 16);
}

static __device__ __forceinline__ unsigned cvt_pk_bf16(float lo, float hi) {
  unsigned r;
  asm("v_cvt_pk_bf16_f32 %0, %1, %2" : "=v"(r) : "v"(lo), "v"(hi));
  return r;
}

static __device__ __forceinline__ float fexp2(float x) {
#if __has_builtin(__builtin_amdgcn_exp2f)
  return __builtin_amdgcn_exp2f(x);           // raw v_exp_f32 (domain here: [-1e30, 11.6])
#else
  float r; asm("v_exp_f32 %0, %1" : "=v"(r) : "v"(x)); return r;
#endif
}

static __device__ __forceinline__ f32x4 mfma16(s16x8 a, s16x8 b, f32x4 c) {
  return __builtin_amdgcn_mfma_f32_16x16x32_bf16(a, b, c, 0, 0, 0);
}
static __device__ __forceinline__ f32x16 mfma32(s16x8 a, s16x8 b, f32x16 c) {
  return __builtin_amdgcn_mfma_f32_32x32x16_bf16(a, b, c, 0, 0, 0);
}

// ---------------- fused prep: weights cast + X concat/cast + AO pad + panel pad ----------------
__global__ __launch_bounds__(256) void k_prep(const float* __restrict__ hid, const float* __restrict__ enc,
    const float* __restrict__ wq, const float* __restrict__ wk,
    const float* __restrict__ wv, const float* __restrict__ wo,
    ushort* __restrict__ Wqkv, ushort* __restrict__ Wo,
    ushort* __restrict__ Xb, ushort* __restrict__ AO,
    ushort* __restrict__ Qb, ushort* __restrict__ Kb, ushort* __restrict__ Vt) {
  int bid = blockIdx.x, tid = threadIdx.x;
  if (bid < 4096) {                              // weights -> bf16
    int q = bid * 256 + tid;
    int reg = q >> 18;
    int off = (q & 262143) << 2;
    const float* sp = (reg == 0) ? wq : (reg == 1) ? wk : (reg == 2) ? wv : wo;
    float4 v = *(const float4*)(sp + off);
    ushort4 o;
    o.x = f2bf(v.x); o.y = f2bf(v.y); o.z = f2bf(v.z); o.w = f2bf(v.w);
    ushort* dst = (reg < 3) ? (Wqkv + ((size_t)reg << 20) + off) : (Wo + off);
    *(ushort4*)dst = o;
  } else if (bid < 8764) {                       // X concat+cast, AO pad rows
    int q = (bid - 4096) * 256 + tid;
    const int XQ = (kMPAD * kD) / 4;
    if (q < XQ) {
      int row = q >> 8;
      int cq = (q & 255) << 2;
      ushort4 o;
      if (row < kBS) {
        int b = row / kS, s = row - b * kS;
        const float* src = (s < kSTXT) ? (enc + (size_t)(b * kSTXT + s) * kD + cq)
                                       : (hid + (size_t)(b * kSVID + (s - kSTXT)) * kD + cq);
        float4 v = *(const float4*)src;
        o.x = f2bf(v.x); o.y = f2bf(v.y); o.z = f2bf(v.z); o.w = f2bf(v.w);
      } else {
        o.x = 0; o.y = 0; o.z = 0; o.w = 0;
      }
      *(ushort4*)(Xb + (size_t)row * kD + cq) = o;
    } else {
      int p = q - XQ;
      ushort4 z; z.x = 0; z.y = 0; z.z = 0; z.w = 0;
      *(ushort4*)(AO + (size_t)kBS * kD + (size_t)p * 4) = z;
    }
  } else {                                       // zero panel pad rows
    int id = (bid - 8764) * 256 + tid;
    int region = id / 30720;
    int r = id - region * 30720;
    if (region < 2) {
      int bh = r / 960, off = r - bh * 960;
      unsigned* p = (unsigned*)((region == 0 ? Qb : Kb) + (size_t)bh * kSPAD * 64 + (size_t)kS * 64);
      p[off] = 0u;
    } else {
      int row = r / 15, off = r - row * 15;
      unsigned* p = (unsigned*)(Vt + (size_t)row * kSPAD + kS);
      p[off] = 0u;
    }
  }
}

// ---------------- fused QKV GEMM + bias + LN + RoPE -> panels ----------------
// 256x128 tile, 8 waves (4M x 2N), dbuf staging with both-sides col-slot XOR swizzle.
__global__ __launch_bounds__(512) void k_gemmqkv(const ushort* __restrict__ A, const ushort* __restrict__ Bm,
    const float* __restrict__ bq, const float* __restrict__ bk, const float* __restrict__ bv,
    const float* __restrict__ lnqw, const float* __restrict__ lnqb,
    const float* __restrict__ lnkw, const float* __restrict__ lnkb,
    const float* __restrict__ cosb, const float* __restrict__ sinb,
    ushort* __restrict__ Qb, ushort* __restrict__ Kb, ushort* __restrict__ Vt) {
  __shared__ ushort lsA[2][8192];                // [256 rows][32 cols] per buffer
  __shared__ ushort lsB[2][4096];                // [128 rows][32 cols] per buffer
  const int K = 1024, nt = 24;
  int bid = blockIdx.x;
  int wg = (bid & 7) * 54 + (bid >> 3);          // XCD swizzle (432 % 8 == 0)
  int mt = wg / nt, ntl = wg - mt * nt;
  int m0 = mt << 8, n0 = ntl << 7;
  int tid = threadIdx.x;
  int w = tid >> 6, l = tid & 63;
  int wm = (w >> 1) << 6, wn = (w & 1) << 6;
  int lr = l & 15, lh = l >> 4;

  f32x4 acc[4][4] = {};

  int cA0 = tid, cA1 = tid + 512, cB = tid;
  int rA0 = cA0 >> 2, rA1 = cA1 >> 2, rB = cB >> 2;
  int sA0 = ((cA0 & 3) ^ ((cA0 >> 3) & 3)) << 3;
  int sA1 = ((cA1 & 3) ^ ((cA1 >> 3) & 3)) << 3;
  int sB  = ((cB & 3) ^ ((cB >> 3) & 3)) << 3;

#define GISSUE(buf, kk0) do {                                              \
    GLOAD16(A + (size_t)(m0 + rA0) * K + (kk0) + sA0, &lsA[buf][cA0 * 8]); \
    GLOAD16(A + (size_t)(m0 + rA1) * K + (kk0) + sA1, &lsA[buf][cA1 * 8]); \
    GLOAD16(Bm + (size_t)(n0 + rB) * K + (kk0) + sB,  &lsB[buf][cB * 8]);  \
  } while (0)

  GISSUE(0, 0);
  for (int kt = 0; kt < 32; ++kt) {
    int cur = kt & 1;
    __builtin_amdgcn_s_barrier();
    if (kt + 1 < 32) {
      GISSUE(cur ^ 1, (kt + 1) * 32);
      asm volatile("s_waitcnt vmcnt(3)" ::: "memory");
    } else {
      asm volatile("s_waitcnt vmcnt(0)" ::: "memory");
    }
    __builtin_amdgcn_s_barrier();
    __builtin_amdgcn_sched_barrier(0);
    s16x8 af[4], bfr[4];
#pragma unroll
    for (int mi = 0; mi < 4; ++mi) {
      int row = wm + mi * 16 + lr;
      int sl = lh ^ ((row >> 1) & 3);
      af[mi] = *(const s16x8*)&lsA[cur][row * 32 + sl * 8];
    }
#pragma unroll
    for (int ni = 0; ni < 4; ++ni) {
      int row = wn + ni * 16 + lr;
      int sl = lh ^ ((row >> 1) & 3);
      bfr[ni] = *(const s16x8*)&lsB[cur][row * 32 + sl * 8];
    }
    __builtin_amdgcn_s_setprio(1);
#pragma unroll
    for (int mi = 0; mi < 4; ++mi)
#pragma unroll
      for (int ni = 0; ni < 4; ++ni)
        acc[mi][ni] = mfma16(af[mi], bfr[ni], acc[mi][ni]);
    __builtin_amdgcn_s_setprio(0);
  }
#undef GISSUE

  int proj = n0 >> 10;
  int cip0 = (n0 & 1023) + wn;
  int hw = cip0 >> 6;
  const float* bias = (proj == 0) ? bq : (proj == 1) ? bk : bv;
  float bi[4];
#pragma unroll
  for (int ni = 0; ni < 4; ++ni) bi[ni] = bias[cip0 + ni * 16 + lr];

  if (proj < 2) {
    const float* lw = proj ? lnkw : lnqw;
    const float* lb = proj ? lnkb : lnqb;
    const float scale = proj ? 1.0f : 0.125f * 1.4426950408889634f;
    float w4[4], b4[4];
#pragma unroll
    for (int ni = 0; ni < 4; ++ni) { w4[ni] = lw[ni * 16 + lr]; b4[ni] = lb[ni * 16 + lr]; }
    ushort* panel = proj ? Kb : Qb;
#pragma unroll
    for (int mi = 0; mi < 4; ++mi) {
#pragma unroll
      for (int r = 0; r < 4; ++r) {
        int grow = m0 + wm + mi * 16 + lh * 4 + r;
        float v0 = acc[mi][0][r] + bi[0], v1 = acc[mi][1][r] + bi[1];
        float v2 = acc[mi][2][r] + bi[2], v3 = acc[mi][3][r] + bi[3];
        float sum = (v0 + v1) + (v2 + v3);
        sum += __shfl_xor(sum, 1); sum += __shfl_xor(sum, 2);
        sum += __shfl_xor(sum, 4); sum += __shfl_xor(sum, 8);
        float mu = sum * (1.0f / 64.0f);
        float d0 = v0 - mu, d1 = v1 - mu, d2 = v2 - mu, d3 = v3 - mu;
        float ss = (d0 * d0 + d1 * d1) + (d2 * d2 + d3 * d3);
        ss += __shfl_xor(ss, 1); ss += __shfl_xor(ss, 2);
        ss += __shfl_xor(ss, 4); ss += __shfl_xor(ss, 8);
        float rstd = rsqrtf(ss * (1.0f / 64.0f) + 1e-5f);
        float n0v = d0 * rstd * w4[0] + b4[0];
        float n1v = d1 * rstd * w4[1] + b4[1];
        float n2v = d2 * rstd * w4[2] + b4[2];
        float n3v = d3 * rstd * w4[3] + b4[3];
        int bb = grow >= kS;
        int s = grow - (bb ? kS : 0);
        bool valid = (grow < kBS) && (s < kS);
        if (valid) {
          if (s >= kSTXT) {
            int pos = s - kSTXT;
            const float* cr = cosb + (size_t)pos * 64;
            const float* sr = sinb + (size_t)pos * 64;
            float sg = (lr & 1) ? 1.0f : -1.0f;
            float p0 = __shfl_xor(n0v, 1), p1 = __shfl_xor(n1v, 1);
            float p2 = __shfl_xor(n2v, 1), p3 = __shfl_xor(n3v, 1);
            n0v = n0v * cr[lr]      + sg * p0 * sr[lr];
            n1v = n1v * cr[16 + lr] + sg * p1 * sr[16 + lr];
            n2v = n2v * cr[32 + lr] + sg * p2 * sr[32 + lr];
            n3v = n3v * cr[48 + lr] + sg * p3 * sr[48 + lr];
          }
          ushort* pr = panel + (size_t)((bb << 4) + hw) * kSPAD * 64 + (size_t)s * 64;
          pr[lr]      = f2bf(n0v * scale);
          pr[16 + lr] = f2bf(n1v * scale);
          pr[32 + lr] = f2bf(n2v * scale);
          pr[48 + lr] = f2bf(n3v * scale);
        }
      }
    }
  } else {
    bool fast = (m0 != 2048) && (m0 != 4352);
#pragma unroll
    for (int mi = 0; mi < 4; ++mi) {
      int grow0 = m0 + wm + mi * 16 + lh * 4;
#pragma unroll
      for (int ni = 0; ni < 4; ++ni) {
        int d = ni * 16 + lr;
        float f0 = acc[mi][ni][0] + bi[ni], f1 = acc[mi][ni][1] + bi[ni];
        float f2 = acc[mi][ni][2] + bi[ni], f3 = acc[mi][ni][3] + bi[ni];
        if (fast) {
          int bb = grow0 >= kS;
          int s0 = grow0 - (bb ? kS : 0);
          unsigned* pr = (unsigned*)(Vt + (size_t)((bb << 4) + hw) * 64 * kSPAD + (size_t)d * kSPAD + s0);
          pr[0] = cvt_pk_bf16(f0, f1);
          pr[1] = cvt_pk_bf16(f2, f3);
        } else {
          float fv[4] = {f0, f1, f2, f3};
#pragma unroll
          for (int j = 0; j < 4; ++j) {
            int grow = grow0 + j;
            int bb = grow >= kS;
            int s = grow - (bb ? kS : 0);
            if (grow < kBS && s < kS)
              Vt[(size_t)((bb << 4) + hw) * 64 * kSPAD + (size_t)d * kSPAD + s] = f2bf(fv[j]);
          }
        }
      }
    }
  }
}

// ---------------- out-projection GEMM: 128x64 tile, 576 blocks, 24KB LDS ----------------
// 4 waves as 2M x 2N (wave sub-tile 64x32, acc[4][2]); dbuf + col-slot XOR swizzle.
__global__ __launch_bounds__(256) void k_gemmo(const ushort* __restrict__ A, const ushort* __restrict__ Bm,
                                               float* __restrict__ OutF, const float* __restrict__ bias) {
  __shared__ ushort lsA[2][4096];                // [128 rows][32 cols]
  __shared__ ushort lsB[2][2048];                // [64 rows][32 cols]
  const int K = 1024, nt = 16;
  int bid = blockIdx.x;
  int wg = (bid & 7) * 72 + (bid >> 3);          // XCD swizzle (576 % 8 == 0)
  int mt = wg / nt, ntl = wg - mt * nt;
  int m0 = mt << 7, n0 = ntl << 6;
  int tid = threadIdx.x;
  int w = tid >> 6, l = tid & 63;
  int wm = (w >> 1) << 6, wn = (w & 1) << 5;     // wm in {0,64}, wn in {0,32}
  int lr = l & 15, lh = l >> 4;

  f32x4 acc[4][2] = {};

  int cA0 = tid, cA1 = tid + 256, cB = tid;      // A: 512 chunks, B: 256 chunks
  int rA0 = cA0 >> 2, rA1 = cA1 >> 2, rB = cB >> 2;
  int sA0 = ((cA0 & 3) ^ ((cA0 >> 3) & 3)) << 3;
  int sA1 = ((cA1 & 3) ^ ((cA1 >> 3) & 3)) << 3;
  int sB  = ((cB & 3) ^ ((cB >> 3) & 3)) << 3;

#define GISSUE(buf, kk0) do {                                              \
    GLOAD16(A + (size_t)(m0 + rA0) * K + (kk0) + sA0, &lsA[buf][cA0 * 8]); \
    GLOAD16(A + (size_t)(m0 + rA1) * K + (kk0) + sA1, &lsA[buf][cA1 * 8]); \
    GLOAD16(Bm + (size_t)(n0 + rB) * K + (kk0) + sB,  &lsB[buf][cB * 8]);  \
  } while (0)

  GISSUE(0, 0);
  for (int kt = 0; kt < 32; ++kt) {
    int cur = kt & 1;
    __builtin_amdgcn_s_barrier();
    if (kt + 1 < 32) {
      GISSUE(cur ^ 1, (kt + 1) * 32);
      asm volatile("s_waitcnt vmcnt(3)" ::: "memory");
    } else {
      asm volatile("s_waitcnt vmcnt(0)" ::: "memory");
    }
    __builtin_amdgcn_s_barrier();
    __builtin_amdgcn_sched_barrier(0);
    s16x8 af[4], bfr[2];
#pragma unroll
    for (int mi = 0; mi < 4; ++mi) {
      int row = wm + mi * 16 + lr;
      int sl = lh ^ ((row >> 1) & 3);
      af[mi] = *(const s16x8*)&lsA[cur][row * 32 + sl * 8];
    }
#pragma unroll
    for (int ni = 0; ni < 2; ++ni) {
      int row = wn + ni * 16 + lr;
      int sl = lh ^ ((row >> 1) & 3);
      bfr[ni] = *(const s16x8*)&lsB[cur][row * 32 + sl * 8];
    }
    __builtin_amdgcn_s_setprio(1);
#pragma unroll
    for (int mi = 0; mi < 4; ++mi)
#pragma unroll
      for (int ni = 0; ni < 2; ++ni)
        acc[mi][ni] = mfma16(af[mi], bfr[ni], acc[mi][ni]);
    __builtin_amdgcn_s_setprio(0);
  }
#undef GISSUE

#pragma unroll
  for (int mi = 0; mi < 4; ++mi) {
#pragma unroll
    for (int ni = 0; ni < 2; ++ni) {
#pragma unroll
      for (int r = 0; r < 4; ++r) {
        int row = m0 + wm + mi * 16 + lh * 4 + r;
        int col = n0 + wn + ni * 16 + lr;
        if (row < kBS) {
          float v = acc[mi][ni][r] + bias[col];
          int b = row / kS, s = row - b * kS;
          size_t o = (s >= kSTXT) ? ((size_t)(b * kSVID + s - kSTXT) * kD + col)
                                  : ((size_t)kB * kSVID * kD + (size_t)(b * kSTXT + s) * kD + col);
          OutF[o] = v;
        }
      }
    }
  }
}

// ---------------- flash attention: 32x32 MFMA, static 3-way KV split (12 tiles/job) ----------------
// grid 1728: (bh, qb128, sp). Fixed-base softmax; raw v_exp_f32; lsum via ones-MFMA.
__global__ __launch_bounds__(256, 4) void k_attn(const ushort* __restrict__ Q, const ushort* __restrict__ K,
                                                 const ushort* __restrict__ Vt,
                                                 ushort* __restrict__ Opb, float* __restrict__ Ml) {
  __shared__ ushort lsK[2][4096];          // [64 kv][64 d] XOR-swizzled
  __shared__ ushort lsVt[2][4096];         // [64 d][64 kv] XOR-swizzled

  int bid = blockIdx.x;
  int wg = (bid & 7) * 216 + (bid >> 3);   // XCD swizzle (1728 % 8 == 0)
  int bq = wg / 3, sp = wg - bq * 3;       // bq in [0,576): bh*18 + qb128
  int bh = bq / 18, qb = bq - bh * 18;
  const ushort* Qp = Q + (size_t)bh * kSPAD * 64;
  const char* Kg = (const char*)(K + (size_t)bh * kSPAD * 64);
  const char* Vg = (const char*)(Vt + (size_t)bh * 64 * kSPAD);

  int tid = threadIdx.x, w = tid >> 6, l = tid & 63;
  int lq = l & 31, h = l >> 5;
  int q0 = qb * 128 + w * 32;

  s16x8 aq[4];                             // Q B-frags: col=q=lq, k_in = d = 16*sl + 8h + j
#pragma unroll
  for (int sl = 0; sl < 4; ++sl)
    aq[sl] = *(const s16x8*)(Qp + (size_t)(q0 + lq) * 64 + sl * 16 + h * 8);

  s16x8 ones;                              // all-ones bf16 A-matrix for lsum MFMA
#pragma unroll
  for (int j = 0; j < 8; ++j) ones[j] = (short)0x3F80;

  f32x16 o0 = {}, o1 = {}, oL = {};        // O^T frags + lsum accumulator

  // staging: 4 x 16B chunks per thread (256 thr: K 8KB + V 8KB)
  int ksrc[2], vsrc[2], kdst[2];
#pragma unroll
  for (int i = 0; i < 2; ++i) {
    int c = tid + 256 * i;                 // chunk id [0,512)
    kdst[i] = c * 16;
    ksrc[i] = (c * 16) ^ (((c >> 3) & 7) << 4);
    int vr = c >> 3;
    vsrc[i] = vr * (kSPAD * 2) + (((c & 7) * 16) ^ ((vr & 7) << 4));
  }

#define ISSUE_TILE(buf, t) do {                                             \
    GLOAD16(Kg + (size_t)(t) * 8192 + ksrc[0], (char*)lsK[buf] + kdst[0]);  \
    GLOAD16(Kg + (size_t)(t) * 8192 + ksrc[1], (char*)lsK[buf] + kdst[1]);  \
    GLOAD16(Vg + (size_t)(t) * 128 + vsrc[0],  (char*)lsVt[buf] + kdst[0]); \
    GLOAD16(Vg + (size_t)(t) * 128 + vsrc[1],  (char*)lsVt[buf] + kdst[1]); \
  } while (0)

  int t0 = sp * 12;
  ISSUE_TILE(0, t0);

  int swz = (lq & 7) << 4;
  for (int tt = 0; tt < 12; ++tt) {
    int t = t0 + tt;
    int cur = tt & 1;
    __builtin_amdgcn_s_barrier();
    if (tt + 1 < 12) {
      ISSUE_TILE(cur ^ 1, t + 1);
      asm volatile("s_waitcnt vmcnt(4)" ::: "memory");
    } else {
      asm volatile("s_waitcnt vmcnt(0)" ::: "memory");
    }
    __builtin_amdgcn_s_barrier();
    __builtin_amdgcn_sched_barrier(0);

    // QK^T swapped (32x32x16): s0 = K[0:32] x Q^T, s1 = K[32:64] x Q^T
    f32x16 s0 = {}, s1 = {};
    __builtin_amdgcn_s_setprio(1);
#pragma unroll
    for (int sl = 0; sl < 4; ++sl) {
      int cb = h * 16 + sl * 32;
      s16x8 kf0 = *(const s16x8*)((const char*)lsK[cur] + ((lq * 128 + cb) ^ swz));
      s16x8 kf1 = *(const s16x8*)((const char*)lsK[cur] + (((lq + 32) * 128 + cb) ^ swz));
      s0 = mfma32(kf0, aq[sl], s0);
      s1 = mfma32(kf1, aq[sl], s1);
    }
    __builtin_amdgcn_s_setprio(0);

    if (t == kNT64 - 1) {                  // mask tail k >= kS (only sp=2, tt=11)
      int kv0 = t * 64;
#pragma unroll
      for (int reg = 0; reg < 16; ++reg) {
        int kl = (reg & 3) + 8 * (reg >> 2) + 4 * h;
        if (kv0 + kl >= kS) s0[reg] = -1e30f;
        if (kv0 + 32 + kl >= kS) s1[reg] = -1e30f;
      }
    }

    // fixed-base softmax: p = exp2(s), raw v_exp_f32 (|s| <= 11.54; -1e30 -> 0)
#pragma unroll
    for (int i = 0; i < 16; ++i) s0[i] = fexp2(s0[i]);
#pragma unroll
    for (int i = 0; i < 16; ++i) s1[i] = fexp2(s1[i]);

    // PV (32x32x16): per 16-k slice, P^T B-frag via 4 cvt_pk + 2 permlane32_swap;
    // lsum accumulated on the MFMA pipe via the all-ones A-matrix.
    __builtin_amdgcn_s_setprio(1);
#pragma unroll
    for (int ks2 = 0; ks2 < 4; ++ks2) {
      unsigned A0, A1, B0, B1;
      if (ks2 == 0) {
        A0 = cvt_pk_bf16(s0[0], s0[1]);  A1 = cvt_pk_bf16(s0[2], s0[3]);
        B0 = cvt_pk_bf16(s0[4], s0[5]);  B1 = cvt_pk_bf16(s0[6], s0[7]);
      } else if (ks2 == 1) {
        A0 = cvt_pk_bf16(s0[8], s0[9]);  A1 = cvt_pk_bf16(s0[10], s0[11]);
        B0 = cvt_pk_bf16(s0[12], s0[13]); B1 = cvt_pk_bf16(s0[14], s0[15]);
      } else if (ks2 == 2) {
        A0 = cvt_pk_bf16(s1[0], s1[1]);  A1 = cvt_pk_bf16(s1[2], s1[3]);
        B0 = cvt_pk_bf16(s1[4], s1[5]);  B1 = cvt_pk_bf16(s1[6], s1[7]);
      } else {
        A0 = cvt_pk_bf16(s1[8], s1[9]);  A1 = cvt_pk_bf16(s1[10], s1[11]);
        B0 = cvt_pk_bf16(s1[12], s1[13]); B1 = cvt_pk_bf16(s1[14], s1[15]);
      }
      asm volatile("v_permlane32_swap_b32 %0, %1" : "+v"(A0), "+v"(B0));
      asm volatile("v_permlane32_swap_b32 %0, %1" : "+v"(A1), "+v"(B1));
      union { unsigned u[4]; s16x8 v; } pu;
      pu.u[0] = A0; pu.u[1] = A1; pu.u[2] = B0; pu.u[3] = B1;
      int cb = h * 16 + ks2 * 32;
      s16x8 vf0 = *(const s16x8*)((const char*)lsVt[cur] + ((lq * 128 + cb) ^ swz));
      s16x8 vf1 = *(const s16x8*)((const char*)lsVt[cur] + (((lq + 32) * 128 + cb) ^ swz));
      o0 = mfma32(vf0, pu.v, o0);
      o1 = mfma32(vf1, pu.v, o1);
      oL = mfma32(ones, pu.v, oL);
    }
    __builtin_amdgcn_s_setprio(0);
  }
#undef ISSUE_TILE

  float lsum = oL[0];                      // every reg/row holds sum_k p[k][lq]

  // store bf16 partials: Opb[sp][bq][q(128)][d(64)], Ml[sp][bq][q(128)]
  ushort* op = Opb + ((size_t)(sp * 576 + bq) << 13);
  int qrow = w * 32 + lq;
#pragma unroll
  for (int g = 0; g < 4; ++g) {
    int d0 = 8 * g + 4 * h;
    uint2 pk;
    pk.x = cvt_pk_bf16(o0[4 * g], o0[4 * g + 1]);
    pk.y = cvt_pk_bf16(o0[4 * g + 2], o0[4 * g + 3]);
    *(uint2*)&op[qrow * 64 + d0] = pk;
    pk.x = cvt_pk_bf16(o1[4 * g], o1[4 * g + 1]);
    pk.y = cvt_pk_bf16(o1[4 * g + 2], o1[4 * g + 3]);
    *(uint2*)&op[qrow * 64 + 32 + d0] = pk;
  }
  float* ml = Ml + ((size_t)(sp * 576 + bq) << 7);
  if (h == 0) ml[qrow] = lsum;
}

// ---------------- combine 3-way split-KV partials -> AO bf16 (fixed base: plain sums) ----------------
__global__ __launch_bounds__(256) void k_combine(const ushort* __restrict__ Opb, const float* __restrict__ Ml,
                                                 ushort* __restrict__ AO) {
  int bq = blockIdx.x;                     // 576 = 32bh x 18 q-blocks
  int bh = bq / 18, q128 = bq - bh * 18;
  int b = bh >> 4, hd = bh & 15;
  int tid = threadIdx.x;
#pragma unroll
  for (int i = 0; i < 8; ++i) {
    int eid = i * 256 + tid;               // 2048 slots = 128q x 16 d4-groups
    int q = eid >> 4;
    int d4 = (eid & 15) << 2;
    int srow = q128 * 128 + q;
    if (srow >= kS) continue;
    float den = 0.0f, e0 = 0.0f, e1 = 0.0f, e2 = 0.0f, e3 = 0.0f;
#pragma unroll
    for (int s = 0; s < 3; ++s) {
      den += Ml[((size_t)(s * 576 + bq) << 7) + q];
      uint2 pk = *(const uint2*)(Opb + ((size_t)(s * 576 + bq) << 13) + (q << 6) + d4);
      e0 += bf2f((short)(pk.x & 0xffffu));
      e1 += bf2f((short)(pk.x >> 16));
      e2 += bf2f((short)(pk.y & 0xffffu));
      e3 += bf2f((short)(pk.y >> 16));
    }
    float inv = 1.0f / den;
    uint2 opk;
    opk.x = (unsigned)f2bf(e0 * inv) | ((unsigned)f2bf(e1 * inv) << 16);
    opk.y = (unsigned)f2bf(e2 * inv) | ((unsigned)f2bf(e3 * inv) << 16);
    *(uint2*)&AO[(size_t)(b * kS + srow) * kD + hd * 64 + d4] = opk;
  }
}

// ---------------- launch ----------------
extern "C" void kernel_launch(void* const* d_in, const int* in_sizes, int n_in,
                              void* d_out, int out_size, void* d_ws, size_t ws_size,
                              hipStream_t stream) {
  const float* hid  = (const float*)d_in[0];
  const float* enc  = (const float*)d_in[1];
  const float* cosb = (const float*)d_in[2];
  const float* sinb = (const float*)d_in[3];
  const float* wq   = (const float*)d_in[4];
  const float* bq   = (const float*)d_in[5];
  const float* wk   = (const float*)d_in[6];
  const float* bk   = (const float*)d_in[7];
  const float* wv   = (const float*)d_in[8];
  const float* bv   = (const float*)d_in[9];
  const float* wo   = (const float*)d_in[10];
  const float* bo   = (const float*)d_in[11];
  const float* lnqw = (const float*)d_in[12];
  const float* lnqb = (const float*)d_in[13];
  const float* lnkw = (const float*)d_in[14];
  const float* lnkb = (const float*)d_in[15];

  if (ws_size < 112197632u) return;

  char* ws = (char*)d_ws;
  ushort* Xb   = (ushort*)(ws);                  // [4608][1024] bf16
  ushort* Wqkv = (ushort*)(ws + 9437184);        // [3072][1024] bf16
  ushort* Wo   = (ushort*)(ws + 15728640);       // [1024][1024] bf16
  ushort* Vtb  = (ushort*)(ws + 17825792);       // [32][64][2304] bf16
  ushort* Opb  = (ushort*)(ws + 27262976);       // [3][576][128][64] bf16 = 28,311,552 B
  float*  Ml   = (float*)(ws + 55574528);        // [3][576][128] f32 = 884,736 B
  ushort* Qb   = (ushort*)(ws + 74448896);       // [32][2304][64] bf16
  ushort* Kb   = (ushort*)(ws + 83886080);       // [32][2304][64] bf16
  ushort* AO   = (ushort*)(ws + 102760448);      // [4608][1024] bf16

  float* out = (float*)d_out;

  k_prep<<<dim3(9124), dim3(256), 0, stream>>>(hid, enc, wq, wk, wv, wo,
      Wqkv, Wo, Xb, AO, Qb, Kb, Vtb);
  k_gemmqkv<<<dim3(432), dim3(512), 0, stream>>>(Xb, Wqkv, bq, bk, bv,
      lnqw, lnqb, lnkw, lnkb, cosb, sinb, Qb, Kb, Vtb);
  k_attn<<<dim3(1728), dim3(256), 0, stream>>>(Qb, Kb, Vtb, Opb, Ml);
  k_combine<<<dim3(576), dim3(256), 0, stream>>>(Opb, Ml, AO);
  k_gemmo<<<dim3(576), dim3(256), 0, stream>>>(AO, Wo, out, bo);
}

// Round 24
// 148.922 us; speedup vs baseline: 3.1462x; 1.0032x over previous
//
#include <hip/hip_runtime.h>
#include <hip/hip_bf16.h>

typedef __attribute__((ext_vector_type(4))) float f32x4;
typedef __attribute__((ext_vector_type(16))) float f32x16;
typedef __attribute__((ext_vector_type(8))) short s16x8;
typedef __attribute__((ext_vector_type(4))) short s16x4;

#define GLOAD16(g, s) __builtin_amdgcn_global_load_lds((const __attribute__((address_space(1))) void*)(g), (__attribute__((address_space(3))) void*)(s), 16, 0, 0)

static constexpr int kB    = 2;
static constexpr int kSTXT = 226;
static constexpr int kSVID = 2048;
static constexpr int kD    = 1024;
static constexpr int kS    = kSTXT + kSVID;   // 2274
static constexpr int kBS   = kB * kS;         // 4548
static constexpr int kMPAD = 4608;            // 36*128 = 18*256
static constexpr int kSPAD = 2304;            // 36*64
static constexpr int kNT64 = kSPAD / 64;      // 36

static __device__ __forceinline__ ushort f2bf(float f) {
  unsigned u = __float_as_uint(f);
  u += 0x7fffu + ((u >> 16) & 1u);            // RNE (finite data only)
  return (ushort)(u >> 16);
}
static __device__ __forceinline__ float bf2f(short x) {
  return __uint_as_float(((unsigned)(ushort)x) << 16);
}

static __device__ __forceinline__ unsigned cvt_pk_bf16(float lo, float hi) {
  unsigned r;
  asm("v_cvt_pk_bf16_f32 %0, %1, %2" : "=v"(r) : "v"(lo), "v"(hi));
  return r;
}

static __device__ __forceinline__ float fexp2(float x) {
#if __has_builtin(__builtin_amdgcn_exp2f)
  return __builtin_amdgcn_exp2f(x);           // raw v_exp_f32 (domain here: [-1e30, 11.6])
#else
  float r; asm("v_exp_f32 %0, %1" : "=v"(r) : "v"(x)); return r;
#endif
}

static __device__ __forceinline__ uint4 pack8(float4 a, float4 b) {
  uint4 o;
  o.x = (unsigned)f2bf(a.x) | ((unsigned)f2bf(a.y) << 16);
  o.y = (unsigned)f2bf(a.z) | ((unsigned)f2bf(a.w) << 16);
  o.z = (unsigned)f2bf(b.x) | ((unsigned)f2bf(b.y) << 16);
  o.w = (unsigned)f2bf(b.z) | ((unsigned)f2bf(b.w) << 16);
  return o;
}

static __device__ __forceinline__ f32x4 mfma16(s16x8 a, s16x8 b, f32x4 c) {
  return __builtin_amdgcn_mfma_f32_16x16x32_bf16(a, b, c, 0, 0, 0);
}
static __device__ __forceinline__ f32x16 mfma32(s16x8 a, s16x8 b, f32x16 c) {
  return __builtin_amdgcn_mfma_f32_32x32x16_bf16(a, b, c, 0, 0, 0);
}

// ---------------- fused prep: weights cast + X concat/cast + AO pad + panel pad ----------------
// 8-elem units: 2x float4 load -> 1x 16B store.
__global__ __launch_bounds__(256) void k_prep(const float* __restrict__ hid, const float* __restrict__ enc,
    const float* __restrict__ wq, const float* __restrict__ wk,
    const float* __restrict__ wv, const float* __restrict__ wo,
    ushort* __restrict__ Wqkv, ushort* __restrict__ Wo,
    ushort* __restrict__ Xb, ushort* __restrict__ AO,
    ushort* __restrict__ Qb, ushort* __restrict__ Kb, ushort* __restrict__ Vt) {
  int bid = blockIdx.x, tid = threadIdx.x;
  if (bid < 2048) {                              // weights -> bf16 (524288 units)
    int u = bid * 256 + tid;
    int reg = u >> 17;                           // 131072 units per 1M-elem matrix
    int off = (u & 131071) << 3;
    const float* sp = (reg == 0) ? wq : (reg == 1) ? wk : (reg == 2) ? wv : wo;
    float4 a = *(const float4*)(sp + off);
    float4 b = *(const float4*)(sp + off + 4);
    ushort* dst = (reg < 3) ? (Wqkv + ((size_t)reg << 20) + off) : (Wo + off);
    *(uint4*)dst = pack8(a, b);
  } else if (bid < 4352) {                       // X concat+cast (589824 units)
    int u = (bid - 2048) * 256 + tid;
    int row = u >> 7;
    int cu = (u & 127) << 3;
    uint4 o;
    if (row < kBS) {
      int b = row / kS, s = row - b * kS;
      const float* src = (s < kSTXT) ? (enc + (size_t)(b * kSTXT + s) * kD + cu)
                                     : (hid + (size_t)(b * kSVID + (s - kSTXT)) * kD + cu);
      float4 a = *(const float4*)src;
      float4 bb = *(const float4*)(src + 4);
      o = pack8(a, bb);
    } else {
      o.x = 0; o.y = 0; o.z = 0; o.w = 0;
    }
    *(uint4*)(Xb + (size_t)row * kD + cu) = o;
  } else if (bid < 4382) {                       // AO pad rows (7680 units)
    int u = (bid - 4352) * 256 + tid;
    uint4 z; z.x = 0; z.y = 0; z.z = 0; z.w = 0;
    *(uint4*)(AO + (size_t)kBS * kD + (size_t)u * 8) = z;
  } else {                                       // zero panel pad rows (92160 u32)
    int id = (bid - 4382) * 256 + tid;
    int region = id / 30720;
    int r = id - region * 30720;
    if (region < 2) {
      int bh = r / 960, off = r - bh * 960;
      unsigned* p = (unsigned*)((region == 0 ? Qb : Kb) + (size_t)bh * kSPAD * 64 + (size_t)kS * 64);
      p[off] = 0u;
    } else {
      int row = r / 15, off = r - row * 15;
      unsigned* p = (unsigned*)(Vt + (size_t)row * kSPAD + kS);
      p[off] = 0u;
    }
  }
}

// ---------------- fused QKV GEMM + bias + LN + RoPE -> panels ----------------
// 256x128 tile, 8 waves (4M x 2N), dbuf staging with both-sides col-slot XOR swizzle.
__global__ __launch_bounds__(512) void k_gemmqkv(const ushort* __restrict__ A, const ushort* __restrict__ Bm,
    const float* __restrict__ bq, const float* __restrict__ bk, const float* __restrict__ bv,
    const float* __restrict__ lnqw, const float* __restrict__ lnqb,
    const float* __restrict__ lnkw, const float* __restrict__ lnkb,
    const float* __restrict__ cosb, const float* __restrict__ sinb,
    ushort* __restrict__ Qb, ushort* __restrict__ Kb, ushort* __restrict__ Vt) {
  __shared__ ushort lsA[2][8192];                // [256 rows][32 cols] per buffer
  __shared__ ushort lsB[2][4096];                // [128 rows][32 cols] per buffer
  const int K = 1024, nt = 24;
  int bid = blockIdx.x;
  int wg = (bid & 7) * 54 + (bid >> 3);          // XCD swizzle (432 % 8 == 0)
  int mt = wg / nt, ntl = wg - mt * nt;
  int m0 = mt << 8, n0 = ntl << 7;
  int tid = threadIdx.x;
  int w = tid >> 6, l = tid & 63;
  int wm = (w >> 1) << 6, wn = (w & 1) << 6;
  int lr = l & 15, lh = l >> 4;

  f32x4 acc[4][4] = {};

  int cA0 = tid, cA1 = tid + 512, cB = tid;
  int rA0 = cA0 >> 2, rA1 = cA1 >> 2, rB = cB >> 2;
  int sA0 = ((cA0 & 3) ^ ((cA0 >> 3) & 3)) << 3;
  int sA1 = ((cA1 & 3) ^ ((cA1 >> 3) & 3)) << 3;
  int sB  = ((cB & 3) ^ ((cB >> 3) & 3)) << 3;

#define GISSUE(buf, kk0) do {                                              \
    GLOAD16(A + (size_t)(m0 + rA0) * K + (kk0) + sA0, &lsA[buf][cA0 * 8]); \
    GLOAD16(A + (size_t)(m0 + rA1) * K + (kk0) + sA1, &lsA[buf][cA1 * 8]); \
    GLOAD16(Bm + (size_t)(n0 + rB) * K + (kk0) + sB,  &lsB[buf][cB * 8]);  \
  } while (0)

  GISSUE(0, 0);
  for (int kt = 0; kt < 32; ++kt) {
    int cur = kt & 1;
    __builtin_amdgcn_s_barrier();
    if (kt + 1 < 32) {
      GISSUE(cur ^ 1, (kt + 1) * 32);
      asm volatile("s_waitcnt vmcnt(3)" ::: "memory");
    } else {
      asm volatile("s_waitcnt vmcnt(0)" ::: "memory");
    }
    __builtin_amdgcn_s_barrier();
    __builtin_amdgcn_sched_barrier(0);
    s16x8 af[4], bfr[4];
#pragma unroll
    for (int mi = 0; mi < 4; ++mi) {
      int row = wm + mi * 16 + lr;
      int sl = lh ^ ((row >> 1) & 3);
      af[mi] = *(const s16x8*)&lsA[cur][row * 32 + sl * 8];
    }
#pragma unroll
    for (int ni = 0; ni < 4; ++ni) {
      int row = wn + ni * 16 + lr;
      int sl = lh ^ ((row >> 1) & 3);
      bfr[ni] = *(const s16x8*)&lsB[cur][row * 32 + sl * 8];
    }
    __builtin_amdgcn_s_setprio(1);
#pragma unroll
    for (int mi = 0; mi < 4; ++mi)
#pragma unroll
      for (int ni = 0; ni < 4; ++ni)
        acc[mi][ni] = mfma16(af[mi], bfr[ni], acc[mi][ni]);
    __builtin_amdgcn_s_setprio(0);
  }
#undef GISSUE

  int proj = n0 >> 10;
  int cip0 = (n0 & 1023) + wn;
  int hw = cip0 >> 6;
  const float* bias = (proj == 0) ? bq : (proj == 1) ? bk : bv;
  float bi[4];
#pragma unroll
  for (int ni = 0; ni < 4; ++ni) bi[ni] = bias[cip0 + ni * 16 + lr];

  if (proj < 2) {
    const float* lw = proj ? lnkw : lnqw;
    const float* lb = proj ? lnkb : lnqb;
    const float scale = proj ? 1.0f : 0.125f * 1.4426950408889634f;
    float w4[4], b4[4];
#pragma unroll
    for (int ni = 0; ni < 4; ++ni) { w4[ni] = lw[ni * 16 + lr]; b4[ni] = lb[ni * 16 + lr]; }
    ushort* panel = proj ? Kb : Qb;
#pragma unroll
    for (int mi = 0; mi < 4; ++mi) {
#pragma unroll
      for (int r = 0; r < 4; ++r) {
        int grow = m0 + wm + mi * 16 + lh * 4 + r;
        float v0 = acc[mi][0][r] + bi[0], v1 = acc[mi][1][r] + bi[1];
        float v2 = acc[mi][2][r] + bi[2], v3 = acc[mi][3][r] + bi[3];
        float sum = (v0 + v1) + (v2 + v3);
        sum += __shfl_xor(sum, 1); sum += __shfl_xor(sum, 2);
        sum += __shfl_xor(sum, 4); sum += __shfl_xor(sum, 8);
        float mu = sum * (1.0f / 64.0f);
        float d0 = v0 - mu, d1 = v1 - mu, d2 = v2 - mu, d3 = v3 - mu;
        float ss = (d0 * d0 + d1 * d1) + (d2 * d2 + d3 * d3);
        ss += __shfl_xor(ss, 1); ss += __shfl_xor(ss, 2);
        ss += __shfl_xor(ss, 4); ss += __shfl_xor(ss, 8);
        float rstd = rsqrtf(ss * (1.0f / 64.0f) + 1e-5f);
        float n0v = d0 * rstd * w4[0] + b4[0];
        float n1v = d1 * rstd * w4[1] + b4[1];
        float n2v = d2 * rstd * w4[2] + b4[2];
        float n3v = d3 * rstd * w4[3] + b4[3];
        int bb = grow >= kS;
        int s = grow - (bb ? kS : 0);
        bool valid = (grow < kBS) && (s < kS);
        if (valid) {
          if (s >= kSTXT) {
            int pos = s - kSTXT;
            const float* cr = cosb + (size_t)pos * 64;
            const float* sr = sinb + (size_t)pos * 64;
            float sg = (lr & 1) ? 1.0f : -1.0f;
            float p0 = __shfl_xor(n0v, 1), p1 = __shfl_xor(n1v, 1);
            float p2 = __shfl_xor(n2v, 1), p3 = __shfl_xor(n3v, 1);
            n0v = n0v * cr[lr]      + sg * p0 * sr[lr];
            n1v = n1v * cr[16 + lr] + sg * p1 * sr[16 + lr];
            n2v = n2v * cr[32 + lr] + sg * p2 * sr[32 + lr];
            n3v = n3v * cr[48 + lr] + sg * p3 * sr[48 + lr];
          }
          ushort* pr = panel + (size_t)((bb << 4) + hw) * kSPAD * 64 + (size_t)s * 64;
          pr[lr]      = f2bf(n0v * scale);
          pr[16 + lr] = f2bf(n1v * scale);
          pr[32 + lr] = f2bf(n2v * scale);
          pr[48 + lr] = f2bf(n3v * scale);
        }
      }
    }
  } else {
    bool fast = (m0 != 2048) && (m0 != 4352);
#pragma unroll
    for (int mi = 0; mi < 4; ++mi) {
      int grow0 = m0 + wm + mi * 16 + lh * 4;
#pragma unroll
      for (int ni = 0; ni < 4; ++ni) {
        int d = ni * 16 + lr;
        float f0 = acc[mi][ni][0] + bi[ni], f1 = acc[mi][ni][1] + bi[ni];
        float f2 = acc[mi][ni][2] + bi[ni], f3 = acc[mi][ni][3] + bi[ni];
        if (fast) {
          int bb = grow0 >= kS;
          int s0 = grow0 - (bb ? kS : 0);
          unsigned* pr = (unsigned*)(Vt + (size_t)((bb << 4) + hw) * 64 * kSPAD + (size_t)d * kSPAD + s0);
          pr[0] = cvt_pk_bf16(f0, f1);
          pr[1] = cvt_pk_bf16(f2, f3);
        } else {
          float fv[4] = {f0, f1, f2, f3};
#pragma unroll
          for (int j = 0; j < 4; ++j) {
            int grow = grow0 + j;
            int bb = grow >= kS;
            int s = grow - (bb ? kS : 0);
            if (grow < kBS && s < kS)
              Vt[(size_t)((bb << 4) + hw) * 64 * kSPAD + (size_t)d * kSPAD + s] = f2bf(fv[j]);
          }
        }
      }
    }
  }
}

// ---------------- out-projection GEMM: 128x64 tile, 576 blocks, 24KB LDS ----------------
__global__ __launch_bounds__(256) void k_gemmo(const ushort* __restrict__ A, const ushort* __restrict__ Bm,
                                               float* __restrict__ OutF, const float* __restrict__ bias) {
  __shared__ ushort lsA[2][4096];                // [128 rows][32 cols]
  __shared__ ushort lsB[2][2048];                // [64 rows][32 cols]
  const int K = 1024, nt = 16;
  int bid = blockIdx.x;
  int wg = (bid & 7) * 72 + (bid >> 3);          // XCD swizzle (576 % 8 == 0)
  int mt = wg / nt, ntl = wg - mt * nt;
  int m0 = mt << 7, n0 = ntl << 6;
  int tid = threadIdx.x;
  int w = tid >> 6, l = tid & 63;
  int wm = (w >> 1) << 6, wn = (w & 1) << 5;
  int lr = l & 15, lh = l >> 4;

  f32x4 acc[4][2] = {};

  int cA0 = tid, cA1 = tid + 256, cB = tid;
  int rA0 = cA0 >> 2, rA1 = cA1 >> 2, rB = cB >> 2;
  int sA0 = ((cA0 & 3) ^ ((cA0 >> 3) & 3)) << 3;
  int sA1 = ((cA1 & 3) ^ ((cA1 >> 3) & 3)) << 3;
  int sB  = ((cB & 3) ^ ((cB >> 3) & 3)) << 3;

#define GISSUE(buf, kk0) do {                                              \
    GLOAD16(A + (size_t)(m0 + rA0) * K + (kk0) + sA0, &lsA[buf][cA0 * 8]); \
    GLOAD16(A + (size_t)(m0 + rA1) * K + (kk0) + sA1, &lsA[buf][cA1 * 8]); \
    GLOAD16(Bm + (size_t)(n0 + rB) * K + (kk0) + sB,  &lsB[buf][cB * 8]);  \
  } while (0)

  GISSUE(0, 0);
  for (int kt = 0; kt < 32; ++kt) {
    int cur = kt & 1;
    __builtin_amdgcn_s_barrier();
    if (kt + 1 < 32) {
      GISSUE(cur ^ 1, (kt + 1) * 32);
      asm volatile("s_waitcnt vmcnt(3)" ::: "memory");
    } else {
      asm volatile("s_waitcnt vmcnt(0)" ::: "memory");
    }
    __builtin_amdgcn_s_barrier();
    __builtin_amdgcn_sched_barrier(0);
    s16x8 af[4], bfr[2];
#pragma unroll
    for (int mi = 0; mi < 4; ++mi) {
      int row = wm + mi * 16 + lr;
      int sl = lh ^ ((row >> 1) & 3);
      af[mi] = *(const s16x8*)&lsA[cur][row * 32 + sl * 8];
    }
#pragma unroll
    for (int ni = 0; ni < 2; ++ni) {
      int row = wn + ni * 16 + lr;
      int sl = lh ^ ((row >> 1) & 3);
      bfr[ni] = *(const s16x8*)&lsB[cur][row * 32 + sl * 8];
    }
    __builtin_amdgcn_s_setprio(1);
#pragma unroll
    for (int mi = 0; mi < 4; ++mi)
#pragma unroll
      for (int ni = 0; ni < 2; ++ni)
        acc[mi][ni] = mfma16(af[mi], bfr[ni], acc[mi][ni]);
    __builtin_amdgcn_s_setprio(0);
  }
#undef GISSUE

#pragma unroll
  for (int mi = 0; mi < 4; ++mi) {
#pragma unroll
    for (int ni = 0; ni < 2; ++ni) {
#pragma unroll
      for (int r = 0; r < 4; ++r) {
        int row = m0 + wm + mi * 16 + lh * 4 + r;
        int col = n0 + wn + ni * 16 + lr;
        if (row < kBS) {
          float v = acc[mi][ni][r] + bias[col];
          int b = row / kS, s = row - b * kS;
          size_t o = (s >= kSTXT) ? ((size_t)(b * kSVID + s - kSTXT) * kD + col)
                                  : ((size_t)kB * kSVID * kD + (size_t)(b * kSTXT + s) * kD + col);
          OutF[o] = v;
        }
      }
    }
  }
}

// ---------------- flash attention: 32x32 MFMA, static 3-way KV split (12 tiles/job) ----------------
// grid 1728: (bh, qb128, sp). Fixed-base softmax; raw v_exp_f32; lsum via ones-MFMA.
__global__ __launch_bounds__(256, 4) void k_attn(const ushort* __restrict__ Q, const ushort* __restrict__ K,
                                                 const ushort* __restrict__ Vt,
                                                 ushort* __restrict__ Opb, float* __restrict__ Ml) {
  __shared__ ushort lsK[2][4096];          // [64 kv][64 d] XOR-swizzled
  __shared__ ushort lsVt[2][4096];         // [64 d][64 kv] XOR-swizzled

  int bid = blockIdx.x;
  int wg = (bid & 7) * 216 + (bid >> 3);   // XCD swizzle (1728 % 8 == 0)
  int bq = wg / 3, sp = wg - bq * 3;       // bq in [0,576): bh*18 + qb128
  int bh = bq / 18, qb = bq - bh * 18;
  const ushort* Qp = Q + (size_t)bh * kSPAD * 64;
  const char* Kg = (const char*)(K + (size_t)bh * kSPAD * 64);
  const char* Vg = (const char*)(Vt + (size_t)bh * 64 * kSPAD);

  int tid = threadIdx.x, w = tid >> 6, l = tid & 63;
  int lq = l & 31, h = l >> 5;
  int q0 = qb * 128 + w * 32;

  s16x8 aq[4];                             // Q B-frags: col=q=lq, k_in = d = 16*sl + 8h + j
#pragma unroll
  for (int sl = 0; sl < 4; ++sl)
    aq[sl] = *(const s16x8*)(Qp + (size_t)(q0 + lq) * 64 + sl * 16 + h * 8);

  s16x8 ones;                              // all-ones bf16 A-matrix for lsum MFMA
#pragma unroll
  for (int j = 0; j < 8; ++j) ones[j] = (short)0x3F80;

  f32x16 o0 = {}, o1 = {}, oL = {};        // O^T frags + lsum accumulator

  // staging: 4 x 16B chunks per thread (256 thr: K 8KB + V 8KB)
  int ksrc[2], vsrc[2], kdst[2];
#pragma unroll
  for (int i = 0; i < 2; ++i) {
    int c = tid + 256 * i;                 // chunk id [0,512)
    kdst[i] = c * 16;
    ksrc[i] = (c * 16) ^ (((c >> 3) & 7) << 4);
    int vr = c >> 3;
    vsrc[i] = vr * (kSPAD * 2) + (((c & 7) * 16) ^ ((vr & 7) << 4));
  }

#define ISSUE_TILE(buf, t) do {                                             \
    GLOAD16(Kg + (size_t)(t) * 8192 + ksrc[0], (char*)lsK[buf] + kdst[0]);  \
    GLOAD16(Kg + (size_t)(t) * 8192 + ksrc[1], (char*)lsK[buf] + kdst[1]);  \
    GLOAD16(Vg + (size_t)(t) * 128 + vsrc[0],  (char*)lsVt[buf] + kdst[0]); \
    GLOAD16(Vg + (size_t)(t) * 128 + vsrc[1],  (char*)lsVt[buf] + kdst[1]); \
  } while (0)

  int t0 = sp * 12;
  ISSUE_TILE(0, t0);

  int swz = (lq & 7) << 4;
  for (int tt = 0; tt < 12; ++tt) {
    int t = t0 + tt;
    int cur = tt & 1;
    __builtin_amdgcn_s_barrier();
    if (tt + 1 < 12) {
      ISSUE_TILE(cur ^ 1, t + 1);
      asm volatile("s_waitcnt vmcnt(4)" ::: "memory");
    } else {
      asm volatile("s_waitcnt vmcnt(0)" ::: "memory");
    }
    __builtin_amdgcn_s_barrier();
    __builtin_amdgcn_sched_barrier(0);

    // QK^T swapped (32x32x16): s0 = K[0:32] x Q^T, s1 = K[32:64] x Q^T
    f32x16 s0 = {}, s1 = {};
    __builtin_amdgcn_s_setprio(1);
#pragma unroll
    for (int sl = 0; sl < 4; ++sl) {
      int cb = h * 16 + sl * 32;
      s16x8 kf0 = *(const s16x8*)((const char*)lsK[cur] + ((lq * 128 + cb) ^ swz));
      s16x8 kf1 = *(const s16x8*)((const char*)lsK[cur] + (((lq + 32) * 128 + cb) ^ swz));
      s0 = mfma32(kf0, aq[sl], s0);
      s1 = mfma32(kf1, aq[sl], s1);
    }
    __builtin_amdgcn_s_setprio(0);

    if (t == kNT64 - 1) {                  // mask tail k >= kS (only sp=2, tt=11)
      int kv0 = t * 64;
#pragma unroll
      for (int reg = 0; reg < 16; ++reg) {
        int kl = (reg & 3) + 8 * (reg >> 2) + 4 * h;
        if (kv0 + kl >= kS) s0[reg] = -1e30f;
        if (kv0 + 32 + kl >= kS) s1[reg] = -1e30f;
      }
    }

    // fixed-base softmax: p = exp2(s), raw v_exp_f32 (|s| <= 11.54; -1e30 -> 0)
#pragma unroll
    for (int i = 0; i < 16; ++i) s0[i] = fexp2(s0[i]);
#pragma unroll
    for (int i = 0; i < 16; ++i) s1[i] = fexp2(s1[i]);

    // PV (32x32x16): per 16-k slice, P^T B-frag via 4 cvt_pk + 2 permlane32_swap;
    // lsum accumulated on the MFMA pipe via the all-ones A-matrix.
    __builtin_amdgcn_s_setprio(1);
#pragma unroll
    for (int ks2 = 0; ks2 < 4; ++ks2) {
      unsigned A0, A1, B0, B1;
      if (ks2 == 0) {
        A0 = cvt_pk_bf16(s0[0], s0[1]);  A1 = cvt_pk_bf16(s0[2], s0[3]);
        B0 = cvt_pk_bf16(s0[4], s0[5]);  B1 = cvt_pk_bf16(s0[6], s0[7]);
      } else if (ks2 == 1) {
        A0 = cvt_pk_bf16(s0[8], s0[9]);  A1 = cvt_pk_bf16(s0[10], s0[11]);
        B0 = cvt_pk_bf16(s0[12], s0[13]); B1 = cvt_pk_bf16(s0[14], s0[15]);
      } else if (ks2 == 2) {
        A0 = cvt_pk_bf16(s1[0], s1[1]);  A1 = cvt_pk_bf16(s1[2], s1[3]);
        B0 = cvt_pk_bf16(s1[4], s1[5]);  B1 = cvt_pk_bf16(s1[6], s1[7]);
      } else {
        A0 = cvt_pk_bf16(s1[8], s1[9]);  A1 = cvt_pk_bf16(s1[10], s1[11]);
        B0 = cvt_pk_bf16(s1[12], s1[13]); B1 = cvt_pk_bf16(s1[14], s1[15]);
      }
      asm volatile("v_permlane32_swap_b32 %0, %1" : "+v"(A0), "+v"(B0));
      asm volatile("v_permlane32_swap_b32 %0, %1" : "+v"(A1), "+v"(B1));
      union { unsigned u[4]; s16x8 v; } pu;
      pu.u[0] = A0; pu.u[1] = A1; pu.u[2] = B0; pu.u[3] = B1;
      int cb = h * 16 + ks2 * 32;
      s16x8 vf0 = *(const s16x8*)((const char*)lsVt[cur] + ((lq * 128 + cb) ^ swz));
      s16x8 vf1 = *(const s16x8*)((const char*)lsVt[cur] + (((lq + 32) * 128 + cb) ^ swz));
      o0 = mfma32(vf0, pu.v, o0);
      o1 = mfma32(vf1, pu.v, o1);
      oL = mfma32(ones, pu.v, oL);
    }
    __builtin_amdgcn_s_setprio(0);
  }
#undef ISSUE_TILE

  float lsum = oL[0];                      // every reg/row holds sum_k p[k][lq]

  // store bf16 partials: Opb[sp][bq][q(128)][d(64)], Ml[sp][bq][q(128)]
  ushort* op = Opb + ((size_t)(sp * 576 + bq) << 13);
  int qrow = w * 32 + lq;
#pragma unroll
  for (int g = 0; g < 4; ++g) {
    int d0 = 8 * g + 4 * h;
    uint2 pk;
    pk.x = cvt_pk_bf16(o0[4 * g], o0[4 * g + 1]);
    pk.y = cvt_pk_bf16(o0[4 * g + 2], o0[4 * g + 3]);
    *(uint2*)&op[qrow * 64 + d0] = pk;
    pk.x = cvt_pk_bf16(o1[4 * g], o1[4 * g + 1]);
    pk.y = cvt_pk_bf16(o1[4 * g + 2], o1[4 * g + 3]);
    *(uint2*)&op[qrow * 64 + 32 + d0] = pk;
  }
  float* ml = Ml + ((size_t)(sp * 576 + bq) << 7);
  if (h == 0) ml[qrow] = lsum;
}

// ---------------- combine 3-way split-KV partials -> AO bf16 (1152 blocks, 64 q each) ----------------
__global__ __launch_bounds__(256) void k_combine(const ushort* __restrict__ Opb, const float* __restrict__ Ml,
                                                 ushort* __restrict__ AO) {
  int bid = blockIdx.x;                    // 1152 = 576 bq x 2 halves
  int bq = bid >> 1, half = bid & 1;
  int bh = bq / 18, q128 = bq - bh * 18;
  int b = bh >> 4, hd = bh & 15;
  int tid = threadIdx.x;
#pragma unroll
  for (int i = 0; i < 4; ++i) {
    int eid = i * 256 + tid;               // 1024 slots = 64q x 16 d4-groups
    int q = half * 64 + (eid >> 4);
    int d4 = (eid & 15) << 2;
    int srow = q128 * 128 + q;
    if (srow >= kS) continue;
    float den = 0.0f, e0 = 0.0f, e1 = 0.0f, e2 = 0.0f, e3 = 0.0f;
#pragma unroll
    for (int s = 0; s < 3; ++s) {
      den += Ml[((size_t)(s * 576 + bq) << 7) + q];
      uint2 pk = *(const uint2*)(Opb + ((size_t)(s * 576 + bq) << 13) + (q << 6) + d4);
      e0 += bf2f((short)(pk.x & 0xffffu));
      e1 += bf2f((short)(pk.x >> 16));
      e2 += bf2f((short)(pk.y & 0xffffu));
      e3 += bf2f((short)(pk.y >> 16));
    }
    float inv = 1.0f / den;
    uint2 opk;
    opk.x = (unsigned)f2bf(e0 * inv) | ((unsigned)f2bf(e1 * inv) << 16);
    opk.y = (unsigned)f2bf(e2 * inv) | ((unsigned)f2bf(e3 * inv) << 16);
    *(uint2*)&AO[(size_t)(b * kS + srow) * kD + hd * 64 + d4] = opk;
  }
}

// ---------------- launch ----------------
extern "C" void kernel_launch(void* const* d_in, const int* in_sizes, int n_in,
                              void* d_out, int out_size, void* d_ws, size_t ws_size,
                              hipStream_t stream) {
  const float* hid  = (const float*)d_in[0];
  const float* enc  = (const float*)d_in[1];
  const float* cosb = (const float*)d_in[2];
  const float* sinb = (const float*)d_in[3];
  const float* wq   = (const float*)d_in[4];
  const float* bq   = (const float*)d_in[5];
  const float* wk   = (const float*)d_in[6];
  const float* bk   = (const float*)d_in[7];
  const float* wv   = (const float*)d_in[8];
  const float* bv   = (const float*)d_in[9];
  const float* wo   = (const float*)d_in[10];
  const float* bo   = (const float*)d_in[11];
  const float* lnqw = (const float*)d_in[12];
  const float* lnqb = (const float*)d_in[13];
  const float* lnkw = (const float*)d_in[14];
  const float* lnkb = (const float*)d_in[15];

  if (ws_size < 112197632u) return;

  char* ws = (char*)d_ws;
  ushort* Xb   = (ushort*)(ws);                  // [4608][1024] bf16
  ushort* Wqkv = (ushort*)(ws + 9437184);        // [3072][1024] bf16
  ushort* Wo   = (ushort*)(ws + 15728640);       // [1024][1024] bf16
  ushort* Vtb  = (ushort*)(ws + 17825792);       // [32][64][2304] bf16
  ushort* Opb  = (ushort*)(ws + 27262976);       // [3][576][128][64] bf16 = 28,311,552 B
  float*  Ml   = (float*)(ws + 55574528);        // [3][576][128] f32 = 884,736 B
  ushort* Qb   = (ushort*)(ws + 74448896);       // [32][2304][64] bf16
  ushort* Kb   = (ushort*)(ws + 83886080);       // [32][2304][64] bf16
  ushort* AO   = (ushort*)(ws + 102760448);      // [4608][1024] bf16

  float* out = (float*)d_out;

  k_prep<<<dim3(4742), dim3(256), 0, stream>>>(hid, enc, wq, wk, wv, wo,
      Wqkv, Wo, Xb, AO, Qb, Kb, Vtb);
  k_gemmqkv<<<dim3(432), dim3(512), 0, stream>>>(Xb, Wqkv, bq, bk, bv,
      lnqw, lnqb, lnkw, lnkb, cosb, sinb, Qb, Kb, Vtb);
  k_attn<<<dim3(1728), dim3(256), 0, stream>>>(Qb, Kb, Vtb, Opb, Ml);
  k_combine<<<dim3(1152), dim3(256), 0, stream>>>(Opb, Ml, AO);
  k_gemmo<<<dim3(576), dim3(256), 0, stream>>>(AO, Wo, out, bo);
}